// Round 1
// baseline (233.187 us; speedup 1.0000x reference)
//
#include <hip/hip_runtime.h>
#include <stdint.h>

// Problem dims (fixed by reference)
#define Bb  4
#define Ss  1024
#define Tt  1024
#define Cc  1024
#define Hh  16
#define HDd 64
#define Kk  1024   // inner dim for all projections (QIN=CTX=C=1024)

typedef __bf16 bf16;
typedef __bf16 bf16x8 __attribute__((ext_vector_type(8)));
typedef float  f32x4  __attribute__((ext_vector_type(4)));
typedef __attribute__((address_space(1))) uint32_t gu32;
typedef __attribute__((address_space(3))) uint32_t lu32;

// async global->LDS, 16B per lane; LDS dest = wave-uniform base + lane*16
__device__ __forceinline__ void load_lds16(const bf16* g, bf16* l) {
    __builtin_amdgcn_global_load_lds((gu32*)g, (lu32*)l, 16, 0, 0);
}

// raw barrier with LDS-only drain: does NOT force vmcnt(0), so global
// prefetch loads stay in flight across it (counted-vmcnt pipelining).
#define BARRIER_LDS() do {                                    \
    asm volatile("s_waitcnt lgkmcnt(0)" ::: "memory");        \
    __builtin_amdgcn_s_barrier();                             \
} while (0)

// ---------------------------------------------------------------------------
// fp32 -> bf16 convert, 8 elems/thread; 7 tensors via blockIdx.y
// ---------------------------------------------------------------------------
__global__ void cvt8(const float* __restrict__ s0, const float* __restrict__ s1,
                     const float* __restrict__ s2, const float* __restrict__ s3,
                     const float* __restrict__ s4, const float* __restrict__ s5,
                     const float* __restrict__ s6,
                     bf16* __restrict__ d0, bf16* __restrict__ d1,
                     bf16* __restrict__ d2, bf16* __restrict__ d3,
                     bf16* __restrict__ d4, bf16* __restrict__ d5,
                     bf16* __restrict__ d6)
{
    const float* s; bf16* d; int n;
    switch (blockIdx.y) {
        case 0: s = s0; d = d0; n = Bb * Ss * Kk; break;
        case 1: s = s1; d = d1; n = Bb * Ss * Kk; break;
        case 2: s = s2; d = d2; n = Bb * Ss * Kk; break;
        case 3: s = s3; d = d3; n = Cc * Kk; break;
        case 4: s = s4; d = d4; n = Cc * Kk; break;
        case 5: s = s5; d = d5; n = Cc * Kk; break;
        default: s = s6; d = d6; n = Cc * Kk; break;
    }
    const int i = (blockIdx.x * blockDim.x + threadIdx.x) * 8;
    if (i >= n) return;
    const float4 a = *(const float4*)(s + i);
    const float4 c = *(const float4*)(s + i + 4);
    bf16x8 o;
    o[0] = (bf16)a.x; o[1] = (bf16)a.y; o[2] = (bf16)a.z; o[3] = (bf16)a.w;
    o[4] = (bf16)c.x; o[5] = (bf16)c.y; o[6] = (bf16)c.z; o[7] = (bf16)c.w;
    *(bf16x8*)(d + i) = o;
}

// ---------------------------------------------------------------------------
// NT-GEMM mainloops, BK=64, XOR-swizzled LDS (chunk ^ row&7).
// NOTE: natural blockIdx mapping kept deliberately — default round-robin
// (f%8 = XCD) gives each XCD a FIXED set of A-tiles (L2-resident) x all
// W-tiles (resident). Round-7's yy-grouping remap thrashed A
// (FETCH 37 -> 104 MB). Do not "optimize" the grid mapping here again.
// ---------------------------------------------------------------------------

// 128x128 C-tile: 4 waves 2x2, each 64x64 = 4x4 MFMA tiles x 2 k-halves
// = 32 MFMA/k-step/wave (m97 density; 2x the old 128x64 variant).
__device__ __forceinline__ void mainloop_128x128(
    const bf16* __restrict__ Ab, const bf16* __restrict__ Wb,
    bf16* As, bf16* Bs, f32x4 acc[4][4])
{
    const int tid  = threadIdx.x;
    const int wid  = tid >> 6;
    const int lane = tid & 63;
    const int l16  = lane & 15;
    const int quad = lane >> 4;
    const int wm   = wid >> 1;
    const int wn   = wid & 1;
    const int r8   = lane >> 3;              // row within 8-row staging chunk
    const int ssw  = ((lane & 7) ^ r8) * 8;  // swizzled k-chunk (elems)

    for (int k0 = 0; k0 < Kk; k0 += 64) {
#pragma unroll
        for (int p = 0; p < 4; p++) {        // A: 128 rows, B: 128 rows
            const int rb = wid * 32 + p * 8;
            load_lds16(Ab + (size_t)(rb + r8) * Kk + k0 + ssw, As + rb * 64);
            load_lds16(Wb + (size_t)(rb + r8) * Kk + k0 + ssw, Bs + rb * 64);
        }
        __syncthreads();   // drains vmcnt(0) -> staging complete
#pragma unroll
        for (int kh = 0; kh < 2; kh++) {
            bf16x8 af[4], bw[4];
#pragma unroll
            for (int i = 0; i < 4; i++)
                af[i] = *(const bf16x8*)(As + (wm * 64 + i * 16 + l16) * 64 +
                                         (((kh * 4 + quad) ^ (l16 & 7)) * 8));
#pragma unroll
            for (int j = 0; j < 4; j++)
                bw[j] = *(const bf16x8*)(Bs + (wn * 64 + j * 16 + l16) * 64 +
                                         (((kh * 4 + quad) ^ (l16 & 7)) * 8));
#pragma unroll
            for (int i = 0; i < 4; i++)
#pragma unroll
                for (int j = 0; j < 4; j++)
                    acc[i][j] = __builtin_amdgcn_mfma_f32_16x16x32_bf16(af[i], bw[j], acc[i][j], 0, 0, 0);
        }
        __syncthreads();   // protect LDS before next stage
    }
}

// 128x64 C-tile: 4 waves 2x2, each 64x32 = 4x2 MFMA tiles x 2 k-halves.
__device__ __forceinline__ void mainloop_128x64(
    const bf16* __restrict__ Ab, const bf16* __restrict__ Wb,
    bf16* As, bf16* Bs, f32x4 acc[4][2])
{
    const int tid  = threadIdx.x;
    const int wid  = tid >> 6;
    const int lane = tid & 63;
    const int l16  = lane & 15;
    const int quad = lane >> 4;
    const int wm   = wid >> 1;
    const int wn   = wid & 1;
    const int r8   = lane >> 3;
    const int ssw  = ((lane & 7) ^ r8) * 8;

    for (int k0 = 0; k0 < Kk; k0 += 64) {
#pragma unroll
        for (int p = 0; p < 4; p++) {        // A: 128 rows
            const int rb = wid * 32 + p * 8;
            load_lds16(Ab + (size_t)(rb + r8) * Kk + k0 + ssw, As + rb * 64);
        }
#pragma unroll
        for (int p = 0; p < 2; p++) {        // B: 64 rows
            const int rb = wid * 16 + p * 8;
            load_lds16(Wb + (size_t)(rb + r8) * Kk + k0 + ssw, Bs + rb * 64);
        }
        __syncthreads();
#pragma unroll
        for (int kh = 0; kh < 2; kh++) {
            bf16x8 af[4], bw[2];
#pragma unroll
            for (int i = 0; i < 4; i++)
                af[i] = *(const bf16x8*)(As + (wm * 64 + i * 16 + l16) * 64 +
                                         (((kh * 4 + quad) ^ (l16 & 7)) * 8));
#pragma unroll
            for (int j = 0; j < 2; j++)
                bw[j] = *(const bf16x8*)(Bs + (wn * 32 + j * 16 + l16) * 64 +
                                         (((kh * 4 + quad) ^ (l16 & 7)) * 8));
#pragma unroll
            for (int i = 0; i < 4; i++)
#pragma unroll
                for (int j = 0; j < 2; j++)
                    acc[i][j] = __builtin_amdgcn_mfma_f32_16x16x32_bf16(af[i], bw[j], acc[i][j], 0, 0, 0);
        }
        __syncthreads();
    }
}

// QKV projections: z selects {Q,K,V}. Q,K -> (B,H,S,HD); V -> (B,H,HD,T)
// Tile 128x128, grid (32, 8, 3) = 768 blocks = 3/CU. Natural mapping.
__global__ __launch_bounds__(256)
void gemm_qkv(const bf16* __restrict__ Aq, const bf16* __restrict__ Ak, const bf16* __restrict__ Av,
              const bf16* __restrict__ Wq, const bf16* __restrict__ Wk, const bf16* __restrict__ Wv,
              const float* __restrict__ bq, const float* __restrict__ bk, const float* __restrict__ bv,
              bf16* __restrict__ Oq, bf16* __restrict__ Ok, bf16* __restrict__ Ov)
{
    __shared__ __align__(16) bf16 As[128 * 64];   // 16 KB
    __shared__ __align__(16) bf16 Bs[128 * 64];   // 16 KB
    const int z = blockIdx.z;
    const bf16*  A    = (z == 0) ? Aq : (z == 1) ? Ak : Av;
    const bf16*  W    = (z == 0) ? Wq : (z == 1) ? Wk : Wv;
    const float* bias = (z == 0) ? bq : (z == 1) ? bk : bv;
    bf16*        O    = (z == 0) ? Oq : (z == 1) ? Ok : Ov;

    f32x4 acc[4][4];
    const f32x4 z4 = {0.f, 0.f, 0.f, 0.f};
#pragma unroll
    for (int i = 0; i < 4; i++)
#pragma unroll
        for (int j = 0; j < 4; j++) acc[i][j] = z4;

    mainloop_128x128(A + (size_t)blockIdx.x * 128 * Kk,
                     W + (size_t)blockIdx.y * 128 * Kk, As, Bs, acc);

    const int tid = threadIdx.x;
    const int wid = tid >> 6, lane = tid & 63;
    const int l16 = lane & 15, quad = lane >> 4;
    const int wm = wid >> 1, wn = wid & 1;
    const int row0 = blockIdx.x * 128 + wm * 64;
    const int col0 = blockIdx.y * 128 + wn * 64;
#pragma unroll
    for (int j = 0; j < 4; j++) {
        const int col = col0 + j * 16 + l16;     // c = h*64 + d
        const float bj = bias[col];
        const int h = col >> 6, d = col & 63;
#pragma unroll
        for (int i = 0; i < 4; i++) {
#pragma unroll
            for (int r = 0; r < 4; r++) {
                const int row = row0 + i * 16 + quad * 4 + r;  // row = b*S + s
                const int b = row >> 10, s = row & 1023;
                const bf16 val = (bf16)(acc[i][j][r] + bj);
                if (z == 2) {
                    Ov[((size_t)((b * Hh + h) * HDd + d)) * Tt + s] = val;  // V^T
                } else {
                    O[((size_t)(b * Hh + h) * Ss + s) * HDd + d] = val;
                }
            }
        }
    }
}

// Output projection: 128x64 tile, grid (32, 16) = 512 blocks = 2/CU.
// Natural mapping. fp32 out, + bias, * rowmask (mask[b,s,0])
__global__ __launch_bounds__(256)
void gemm_out(const bf16* __restrict__ A, const bf16* __restrict__ W,
              const float* __restrict__ bias, const int* __restrict__ mask,
              float* __restrict__ out)
{
    __shared__ __align__(16) bf16 As[128 * 64];   // 16 KB
    __shared__ __align__(16) bf16 Bs[64 * 64];    // 8 KB
    f32x4 acc[4][2];
    const f32x4 z4 = {0.f, 0.f, 0.f, 0.f};
#pragma unroll
    for (int i = 0; i < 4; i++)
#pragma unroll
        for (int j = 0; j < 2; j++) acc[i][j] = z4;

    mainloop_128x64(A + (size_t)blockIdx.x * 128 * Kk,
                    W + (size_t)blockIdx.y * 64 * Kk, As, Bs, acc);

    const int tid = threadIdx.x;
    const int wid = tid >> 6, lane = tid & 63;
    const int l16 = lane & 15, quad = lane >> 4;
    const int wm = wid >> 1, wn = wid & 1;
    const int row0 = blockIdx.x * 128 + wm * 64;
    const int col0 = blockIdx.y * 64 + wn * 32;
#pragma unroll
    for (int j = 0; j < 2; j++) {
        const int col = col0 + j * 16 + l16;
        const float bj = bias[col];
#pragma unroll
        for (int i = 0; i < 4; i++) {
#pragma unroll
            for (int r = 0; r < 4; r++) {
                const int row = row0 + i * 16 + quad * 4 + r;
                const float mval = (mask[(size_t)row * Tt] != 0) ? 1.f : 0.f;
                out[(size_t)row * Cc + col] = (acc[i][j][r] + bj) * mval;
            }
        }
    }
}

// ---------------------------------------------------------------------------
// Flash attention v2 + XCD swizzle (KEEP): flat grid 1024; all 16 q-blocks of
// one (b,h) land on the same XCD so K/V (256 KB per bh) stays L2-resident.
//
// Pipelined staging (T14 async-STAGE): K/V tiles go global->reg->LDS with the
// NEXT tile's loads (and its mask dwords) issued before the CURRENT tile's
// compute. Barriers are raw s_barrier + lgkmcnt(0) only — __syncthreads would
// emit s_waitcnt vmcnt(0) and drain the prefetch. Same LDS layout/swizzle as
// before; ds_write_b128 per lane is linear -> conflict-free.
// ---------------------------------------------------------------------------
__global__ __launch_bounds__(256, 4)
void attn(const bf16* __restrict__ Q, const bf16* __restrict__ Kp, const bf16* __restrict__ Vt,
          const int* __restrict__ mask, bf16* __restrict__ X)
{
    __shared__ __align__(16) bf16 Ks[64 * 64];    // [t_local][d]  (swizzled)
    __shared__ __align__(16) bf16 Vs[64 * 64];    // [d][t_local]  (swizzled)
    __shared__ __align__(16) bf16 Ps[4][16 * 72]; // per-wave P, row stride 72
    const int g   = blockIdx.x;
    const int xcd = g & 7, idx = g >> 3;          // idx in [0,128)
    const int bh  = xcd * 8 + (idx >> 4);         // [0,64): 8 bh per XCD
    const int qblk = idx & 15;                    // q-block [0,16)
    const int b = bh >> 4, h = bh & 15;
    const int tid = threadIdx.x, wid = tid >> 6, lane = tid & 63;
    const int l16 = lane & 15, quad = lane >> 4;
    const bf16* Qbh = Q  + (size_t)bh * Ss * HDd;
    const bf16* Kbh = Kp + (size_t)bh * Tt * HDd;
    const bf16* Vbh = Vt + (size_t)bh * HDd * Tt;
    const int*  mb  = mask + (size_t)b * Ss * Tt;  // mb[t] = mask[b,0,t]
    const int q0 = qblk * 64 + wid * 16;
    bf16* Psw = &Ps[wid][0];

    // Q fragments (A-layout): rows q0+l16, k halves [0,32) and [32,64)
    const bf16x8 qf0 = *(const bf16x8*)(Qbh + (size_t)(q0 + l16) * HDd + quad * 8);
    const bf16x8 qf1 = *(const bf16x8*)(Qbh + (size_t)(q0 + l16) * HDd + 32 + quad * 8);

    float ls[4];
    f32x4 o[4];
    const f32x4 z4 = {0.f, 0.f, 0.f, 0.f};
#pragma unroll
    for (int r = 0; r < 4; r++) ls[r] = 0.f;
#pragma unroll
    for (int dblk = 0; dblk < 4; dblk++) o[dblk] = z4;

    // staging lane decomposition: 8 lanes per 64-elem (128B) row
    const int srow = lane >> 3;          // 0..7: row within an 8-row chunk
    const int schk = lane & 7;           // 0..7: 16B chunk within the row
    const int sswz = (schk ^ srow) * 8;  // swizzled source element offset
    const int c80 = wid * 2, c81 = wid * 2 + 1;   // this wave's 8-row chunks

    // per-thread global bases (tile offset added per tile) and LDS dests
    const bf16* kg0 = Kbh + (size_t)(c80 * 8 + srow) * HDd + sswz;
    const bf16* kg1 = Kbh + (size_t)(c81 * 8 + srow) * HDd + sswz;
    const bf16* vg0 = Vbh + (size_t)(c80 * 8 + srow) * Tt + sswz;
    const bf16* vg1 = Vbh + (size_t)(c81 * 8 + srow) * Tt + sswz;
    bf16* kd0 = Ks + c80 * 512 + lane * 8;
    bf16* kd1 = Ks + c81 * 512 + lane * 8;
    bf16* vd0 = Vs + c80 * 512 + lane * 8;
    bf16* vd1 = Vs + c81 * 512 + lane * 8;

    bf16x8 ka0, ka1, va0, va1;              // reg buffer A
    bf16x8 kb0, kb1, vb0, vb1;              // reg buffer B
    int mA0, mA1, mA2, mA3, mB0, mB1, mB2, mB3;

#define LOADA(KT) do { const int _kt = (KT);                          \
    ka0 = *(const bf16x8*)(kg0 + (size_t)_kt * HDd);                  \
    ka1 = *(const bf16x8*)(kg1 + (size_t)_kt * HDd);                  \
    va0 = *(const bf16x8*)(vg0 + _kt);                                \
    va1 = *(const bf16x8*)(vg1 + _kt);                                \
    mA0 = mb[_kt + l16];      mA1 = mb[_kt + 16 + l16];               \
    mA2 = mb[_kt + 32 + l16]; mA3 = mb[_kt + 48 + l16]; } while (0)
#define LOADB(KT) do { const int _kt = (KT);                          \
    kb0 = *(const bf16x8*)(kg0 + (size_t)_kt * HDd);                  \
    kb1 = *(const bf16x8*)(kg1 + (size_t)_kt * HDd);                  \
    vb0 = *(const bf16x8*)(vg0 + _kt);                                \
    vb1 = *(const bf16x8*)(vg1 + _kt);                                \
    mB0 = mb[_kt + l16];      mB1 = mb[_kt + 16 + l16];               \
    mB2 = mb[_kt + 32 + l16]; mB3 = mb[_kt + 48 + l16]; } while (0)
#define STOREA() do {                                                 \
    *(bf16x8*)kd0 = ka0; *(bf16x8*)kd1 = ka1;                         \
    *(bf16x8*)vd0 = va0; *(bf16x8*)vd1 = va1; } while (0)
#define STOREB() do {                                                 \
    *(bf16x8*)kd0 = kb0; *(bf16x8*)kd1 = kb1;                         \
    *(bf16x8*)vd0 = vb0; *(bf16x8*)vd1 = vb1; } while (0)

    auto compute = [&](int m0, int m1, int m2, int m3) {
        // QK^T: 4 n-blocks of 16 keys, 2 k-halves of 32 channels
        f32x4 sc[4];
#pragma unroll
        for (int nb = 0; nb < 4; nb++) sc[nb] = z4;
#pragma unroll
        for (int nb = 0; nb < 4; nb++) {
            const bf16* krow = Ks + (nb * 16 + l16) * 64;
            const bf16x8 kf0 = *(const bf16x8*)(krow + ((quad       ^ (l16 & 7)) * 8));
            const bf16x8 kf1 = *(const bf16x8*)(krow + (((4 + quad) ^ (l16 & 7)) * 8));
            sc[nb] = __builtin_amdgcn_mfma_f32_16x16x32_bf16(qf0, kf0, sc[nb], 0, 0, 0);
            sc[nb] = __builtin_amdgcn_mfma_f32_16x16x32_bf16(qf1, kf1, sc[nb], 0, 0, 0);
        }

        // softmax numerator (no max subtraction) + P store (C->A layout)
        const int mm[4] = {m0, m1, m2, m3};
#pragma unroll
        for (int nb = 0; nb < 4; nb++) {
            const float madd = mm[nb] ? 0.f : -1e30f;
#pragma unroll
            for (int r = 0; r < 4; r++) {
                const float p = __expf(sc[nb][r] * 0.125f + madd);
                ls[r] += p;
                Psw[(quad * 4 + r) * 72 + nb * 16 + l16] = (bf16)p;
            }
        }

        // O += P @ V : A = P (rows q), B = V^T (rows d), k = t in 2 halves
#pragma unroll
        for (int kh = 0; kh < 2; kh++) {
            const bf16x8 pf = *(const bf16x8*)(Psw + l16 * 72 + kh * 32 + quad * 8);
#pragma unroll
            for (int dblk = 0; dblk < 4; dblk++) {
                const bf16x8 vf = *(const bf16x8*)(Vs + (dblk * 16 + l16) * 64 +
                                                   (((kh * 4 + quad) ^ (l16 & 7)) * 8));
                o[dblk] = __builtin_amdgcn_mfma_f32_16x16x32_bf16(pf, vf, o[dblk], 0, 0, 0);
            }
        }
    };

    // prologue: tile 0 into reg buffer A
    LOADA(0);

    for (int kt = 0; kt < Tt; kt += 128) {
        // ---- tile kt (regs A) ----
        BARRIER_LDS();                 // all waves done reading prev tile's LDS
        LOADB(kt + 64);                // prefetch next tile (kt+64 <= 960 always)
        STOREA();                      // compiler waits vmcnt(N) for A regs only
        BARRIER_LDS();                 // ds_writes visible to all waves
        compute(mA0, mA1, mA2, mA3);

        // ---- tile kt+64 (regs B) ----
        BARRIER_LDS();
        LOADA((kt + 128 < Tt) ? (kt + 128) : (Tt - 64));  // last one redundant
        STOREB();
        BARRIER_LDS();
        compute(mB0, mB1, mB2, mB3);
    }
#undef LOADA
#undef LOADB
#undef STOREA
#undef STOREB

    // row sums: reduce ls across the 16 l16 lanes
#pragma unroll
    for (int off = 1; off <= 8; off <<= 1)
#pragma unroll
        for (int r = 0; r < 4; r++)
            ls[r] += __shfl_xor(ls[r], off, 64);
    float inv[4];
#pragma unroll
    for (int r = 0; r < 4; r++) inv[r] = 1.f / ls[r];

#pragma unroll
    for (int dblk = 0; dblk < 4; dblk++) {
#pragma unroll
        for (int r = 0; r < 4; r++) {
            const int srow_q = q0 + quad * 4 + r;
            const int d = dblk * 16 + l16;
            X[(size_t)(b * Ss + srow_q) * Cc + h * HDd + d] = (bf16)(o[dblk][r] * inv[r]);
        }
    }
}

// ---------------------------------------------------------------------------
extern "C" void kernel_launch(void* const* d_in, const int* in_sizes, int n_in,
                              void* d_out, int out_size, void* d_ws, size_t ws_size,
                              hipStream_t stream)
{
    const float* query = (const float*)d_in[0];
    const float* key   = (const float*)d_in[1];
    const float* value = (const float*)d_in[2];
    const int*   mask  = (const int*)d_in[3];
    const float* Wq = (const float*)d_in[4];
    const float* bq = (const float*)d_in[5];
    const float* Wk = (const float*)d_in[6];
    const float* bk = (const float*)d_in[7];
    const float* Wv = (const float*)d_in[8];
    const float* bv = (const float*)d_in[9];
    const float* Wo = (const float*)d_in[10];
    const float* bo = (const float*)d_in[11];
    float* out = (float*)d_out;

    char* ws = (char*)d_ws;
    const size_t MB = 1024 * 1024;
    bf16* qb  = (bf16*)(ws + 0 * MB);
    bf16* kb  = (bf16*)(ws + 8 * MB);
    bf16* vb  = (bf16*)(ws + 16 * MB);
    bf16* wqb = (bf16*)(ws + 24 * MB);
    bf16* wkb = (bf16*)(ws + 26 * MB);
    bf16* wvb = (bf16*)(ws + 28 * MB);
    bf16* wob = (bf16*)(ws + 30 * MB);
    bf16* Qp  = (bf16*)(ws + 32 * MB);   // (B,H,S,HD) bf16
    bf16* Kpp = (bf16*)(ws + 40 * MB);   // (B,H,T,HD) bf16
    bf16* Vtp = (bf16*)(ws + 48 * MB);   // (B,H,HD,T) bf16
    bf16* Xb  = (bf16*)(ws + 56 * MB);   // attn out (B*S, C) bf16

    cvt8<<<dim3(2048, 7), 256, 0, stream>>>(query, key, value, Wq, Wk, Wv, Wo,
                                            qb, kb, vb, wqb, wkb, wvb, wob);
    gemm_qkv<<<dim3(32, 8, 3), 256, 0, stream>>>(qb, kb, vb, wqb, wkb, wvb,
                                                 bq, bk, bv, Qp, Kpp, Vtp);
    attn<<<dim3(1024), 256, 0, stream>>>(Qp, Kpp, Vtp, mask, Xb);
    gemm_out<<<dim3(32, 16), 256, 0, stream>>>(Xb, wob, bo, mask, out);
}

// Round 2
// 232.553 us; speedup vs baseline: 1.0027x; 1.0027x over previous
//
#include <hip/hip_runtime.h>
#include <stdint.h>

// Problem dims (fixed by reference)
#define Bb  4
#define Ss  1024
#define Tt  1024
#define Cc  1024
#define Hh  16
#define HDd 64
#define Kk  1024   // inner dim for all projections (QIN=CTX=C=1024)

typedef __bf16 bf16;
typedef __bf16 bf16x8 __attribute__((ext_vector_type(8)));
typedef float  f32x4  __attribute__((ext_vector_type(4)));
typedef __attribute__((address_space(1))) uint32_t gu32;
typedef __attribute__((address_space(3))) uint32_t lu32;

// async global->LDS, 16B per lane; LDS dest = wave-uniform base + lane*16
__device__ __forceinline__ void load_lds16(const bf16* g, bf16* l) {
    __builtin_amdgcn_global_load_lds((gu32*)g, (lu32*)l, 16, 0, 0);
}

// raw barrier with LDS-only drain: does NOT force vmcnt(0), so global
// prefetch loads stay in flight across it (counted-vmcnt pipelining).
#define BARRIER_LDS() do {                                    \
    asm volatile("s_waitcnt lgkmcnt(0)" ::: "memory");        \
    __builtin_amdgcn_s_barrier();                             \
} while (0)

// full drain barrier for the 2-phase GEMM pipeline (one per k-step)
#define BARRIER_VM() do {                                     \
    asm volatile("s_waitcnt vmcnt(0)" ::: "memory");          \
    __builtin_amdgcn_s_barrier();                             \
} while (0)

// ---------------------------------------------------------------------------
// fp32 -> bf16 convert, 8 elems/thread; 7 tensors via blockIdx.y
// ---------------------------------------------------------------------------
__global__ void cvt8(const float* __restrict__ s0, const float* __restrict__ s1,
                     const float* __restrict__ s2, const float* __restrict__ s3,
                     const float* __restrict__ s4, const float* __restrict__ s5,
                     const float* __restrict__ s6,
                     bf16* __restrict__ d0, bf16* __restrict__ d1,
                     bf16* __restrict__ d2, bf16* __restrict__ d3,
                     bf16* __restrict__ d4, bf16* __restrict__ d5,
                     bf16* __restrict__ d6)
{
    const float* s; bf16* d; int n;
    switch (blockIdx.y) {
        case 0: s = s0; d = d0; n = Bb * Ss * Kk; break;
        case 1: s = s1; d = d1; n = Bb * Ss * Kk; break;
        case 2: s = s2; d = d2; n = Bb * Ss * Kk; break;
        case 3: s = s3; d = d3; n = Cc * Kk; break;
        case 4: s = s4; d = d4; n = Cc * Kk; break;
        case 5: s = s5; d = d5; n = Cc * Kk; break;
        default: s = s6; d = d6; n = Cc * Kk; break;
    }
    const int i = (blockIdx.x * blockDim.x + threadIdx.x) * 8;
    if (i >= n) return;
    const float4 a = *(const float4*)(s + i);
    const float4 c = *(const float4*)(s + i + 4);
    bf16x8 o;
    o[0] = (bf16)a.x; o[1] = (bf16)a.y; o[2] = (bf16)a.z; o[3] = (bf16)a.w;
    o[4] = (bf16)c.x; o[5] = (bf16)c.y; o[6] = (bf16)c.z; o[7] = (bf16)c.w;
    *(bf16x8*)(d + i) = o;
}

// ---------------------------------------------------------------------------
// NT-GEMM mainloop, 128x64 C-tile (the PROVEN tile — 128x128 regressed in R1:
// occupancy collapsed 26%->13%, dur 47->60 us; do not retry it with this
// sync structure). BK=64, XOR-swizzled LDS (chunk ^ row&7).
//
// 2-PHASE PIPELINE (T3 minimum template): LDS double-buffered; next k-tile's
// global_load_lds issued BEFORE the current tile's ds_read+MFMA, and a single
// vmcnt(0)+s_barrier per k-step. Loads stay in flight across the whole
// compute phase instead of being drained immediately after issue.
//
// NOTE: natural blockIdx mapping kept deliberately — default round-robin
// (f%8 = XCD) gives each XCD a FIXED set of A-tiles (L2-resident) x all
// W-tiles (resident). Round-7's yy-grouping remap thrashed A
// (FETCH 37 -> 104 MB). Do not "optimize" the grid mapping here again.
// ---------------------------------------------------------------------------
__device__ __forceinline__ void mainloop_128x64_2ph(
    const bf16* __restrict__ Ab, const bf16* __restrict__ Wb,
    bf16* As, bf16* Bs, f32x4 acc[4][2])
{
    const int tid  = threadIdx.x;
    const int wid  = tid >> 6;
    const int lane = tid & 63;
    const int l16  = lane & 15;
    const int quad = lane >> 4;
    const int wm   = wid >> 1;
    const int wn   = wid & 1;
    const int r8   = lane >> 3;              // row within 8-row staging chunk
    const int ssw  = ((lane & 7) ^ r8) * 8;  // swizzled k-chunk (elems)

    // stage k-tile k0 into LDS buffer buf (6 x global_load_lds_dwordx4/thread)
    auto stage = [&](int buf, int k0) {
        bf16* Asb = As + buf * (128 * 64);
        bf16* Bsb = Bs + buf * (64 * 64);
#pragma unroll
        for (int p = 0; p < 4; p++) {        // A: 128 rows
            const int rb = wid * 32 + p * 8;
            load_lds16(Ab + (size_t)(rb + r8) * Kk + k0 + ssw, Asb + rb * 64);
        }
#pragma unroll
        for (int p = 0; p < 2; p++) {        // B: 64 rows
            const int rb = wid * 16 + p * 8;
            load_lds16(Wb + (size_t)(rb + r8) * Kk + k0 + ssw, Bsb + rb * 64);
        }
    };

    // compute one k-tile from LDS buffer base pointers
    auto compute = [&](const bf16* Asb, const bf16* Bsb) {
#pragma unroll
        for (int kh = 0; kh < 2; kh++) {
            bf16x8 af[4], bw[2];
#pragma unroll
            for (int i = 0; i < 4; i++)
                af[i] = *(const bf16x8*)(Asb + (wm * 64 + i * 16 + l16) * 64 +
                                         (((kh * 4 + quad) ^ (l16 & 7)) * 8));
#pragma unroll
            for (int j = 0; j < 2; j++)
                bw[j] = *(const bf16x8*)(Bsb + (wn * 32 + j * 16 + l16) * 64 +
                                         (((kh * 4 + quad) ^ (l16 & 7)) * 8));
#pragma unroll
            for (int i = 0; i < 4; i++)
#pragma unroll
                for (int j = 0; j < 2; j++)
                    acc[i][j] = __builtin_amdgcn_mfma_f32_16x16x32_bf16(af[i], bw[j], acc[i][j], 0, 0, 0);
        }
    };

    // prologue: tile 0 into buffer 0, full drain
    stage(0, 0);
    BARRIER_VM();

    // steady state: 2 k-tiles per iteration (static buffer indices)
    for (int k0 = 0; k0 < Kk; k0 += 128) {
        stage(1, k0 + 64);                   // always valid: k0+64 <= Kk-64
        compute(As, Bs);                     // buffer 0
        BARRIER_VM();                        // buf1 staged; buf0 reads done
        if (k0 + 128 < Kk) stage(0, k0 + 128);
        compute(As + 128 * 64, Bs + 64 * 64);// buffer 1
        BARRIER_VM();
    }
}

// QKV projections: z selects {Q,K,V}. Q,K -> (B,H,S,HD); V -> (B,H,HD,T)
// Tile 128x64, grid (32, 16, 3) = 1536 blocks. Natural mapping.
__global__ __launch_bounds__(256)
void gemm_qkv(const bf16* __restrict__ Aq, const bf16* __restrict__ Ak, const bf16* __restrict__ Av,
              const bf16* __restrict__ Wq, const bf16* __restrict__ Wk, const bf16* __restrict__ Wv,
              const float* __restrict__ bq, const float* __restrict__ bk, const float* __restrict__ bv,
              bf16* __restrict__ Oq, bf16* __restrict__ Ok, bf16* __restrict__ Ov)
{
    __shared__ __align__(16) bf16 As[2 * 128 * 64];   // 32 KB (double-buffered)
    __shared__ __align__(16) bf16 Bs[2 * 64 * 64];    // 16 KB
    const int z = blockIdx.z;
    const bf16*  A    = (z == 0) ? Aq : (z == 1) ? Ak : Av;
    const bf16*  W    = (z == 0) ? Wq : (z == 1) ? Wk : Wv;
    const float* bias = (z == 0) ? bq : (z == 1) ? bk : bv;
    bf16*        O    = (z == 0) ? Oq : (z == 1) ? Ok : Ov;

    f32x4 acc[4][2];
    const f32x4 z4 = {0.f, 0.f, 0.f, 0.f};
#pragma unroll
    for (int i = 0; i < 4; i++)
#pragma unroll
        for (int j = 0; j < 2; j++) acc[i][j] = z4;

    mainloop_128x64_2ph(A + (size_t)blockIdx.x * 128 * Kk,
                        W + (size_t)blockIdx.y * 64 * Kk, As, Bs, acc);

    const int tid = threadIdx.x;
    const int wid = tid >> 6, lane = tid & 63;
    const int l16 = lane & 15, quad = lane >> 4;
    const int wm = wid >> 1, wn = wid & 1;
    const int row0 = blockIdx.x * 128 + wm * 64;
    const int col0 = blockIdx.y * 64 + wn * 32;
#pragma unroll
    for (int j = 0; j < 2; j++) {
        const int col = col0 + j * 16 + l16;     // c = h*64 + d
        const float bj = bias[col];
        const int h = col >> 6, d = col & 63;
#pragma unroll
        for (int i = 0; i < 4; i++) {
#pragma unroll
            for (int r = 0; r < 4; r++) {
                const int row = row0 + i * 16 + quad * 4 + r;  // row = b*S + s
                const int b = row >> 10, s = row & 1023;
                const bf16 val = (bf16)(acc[i][j][r] + bj);
                if (z == 2) {
                    Ov[((size_t)((b * Hh + h) * HDd + d)) * Tt + s] = val;  // V^T
                } else {
                    O[((size_t)(b * Hh + h) * Ss + s) * HDd + d] = val;
                }
            }
        }
    }
}

// Output projection: 128x64 tile, grid (32, 16) = 512 blocks.
// Natural mapping. fp32 out, + bias, * rowmask (mask[b,s,0])
__global__ __launch_bounds__(256)
void gemm_out(const bf16* __restrict__ A, const bf16* __restrict__ W,
              const float* __restrict__ bias, const int* __restrict__ mask,
              float* __restrict__ out)
{
    __shared__ __align__(16) bf16 As[2 * 128 * 64];   // 32 KB
    __shared__ __align__(16) bf16 Bs[2 * 64 * 64];    // 16 KB
    f32x4 acc[4][2];
    const f32x4 z4 = {0.f, 0.f, 0.f, 0.f};
#pragma unroll
    for (int i = 0; i < 4; i++)
#pragma unroll
        for (int j = 0; j < 2; j++) acc[i][j] = z4;

    mainloop_128x64_2ph(A + (size_t)blockIdx.x * 128 * Kk,
                        W + (size_t)blockIdx.y * 64 * Kk, As, Bs, acc);

    const int tid = threadIdx.x;
    const int wid = tid >> 6, lane = tid & 63;
    const int l16 = lane & 15, quad = lane >> 4;
    const int wm = wid >> 1, wn = wid & 1;
    const int row0 = blockIdx.x * 128 + wm * 64;
    const int col0 = blockIdx.y * 64 + wn * 32;
#pragma unroll
    for (int j = 0; j < 2; j++) {
        const int col = col0 + j * 16 + l16;
        const float bj = bias[col];
#pragma unroll
        for (int i = 0; i < 4; i++) {
#pragma unroll
            for (int r = 0; r < 4; r++) {
                const int row = row0 + i * 16 + quad * 4 + r;
                const float mval = (mask[(size_t)row * Tt] != 0) ? 1.f : 0.f;
                out[(size_t)row * Cc + col] = (acc[i][j][r] + bj) * mval;
            }
        }
    }
}

// ---------------------------------------------------------------------------
// Flash attention v2 + XCD swizzle (KEEP): flat grid 1024; all 16 q-blocks of
// one (b,h) land on the same XCD so K/V (256 KB per bh) stays L2-resident.
//
// Pipelined staging (T14 async-STAGE): K/V tiles go global->reg->LDS with the
// NEXT tile's loads (and its mask dwords) issued before the CURRENT tile's
// compute. Barriers are raw s_barrier + lgkmcnt(0) only — __syncthreads would
// emit s_waitcnt vmcnt(0) and drain the prefetch. Same LDS layout/swizzle as
// before; ds_write_b128 per lane is linear -> conflict-free.
// ---------------------------------------------------------------------------
__global__ __launch_bounds__(256, 4)
void attn(const bf16* __restrict__ Q, const bf16* __restrict__ Kp, const bf16* __restrict__ Vt,
          const int* __restrict__ mask, bf16* __restrict__ X)
{
    __shared__ __align__(16) bf16 Ks[64 * 64];    // [t_local][d]  (swizzled)
    __shared__ __align__(16) bf16 Vs[64 * 64];    // [d][t_local]  (swizzled)
    __shared__ __align__(16) bf16 Ps[4][16 * 72]; // per-wave P, row stride 72
    const int g   = blockIdx.x;
    const int xcd = g & 7, idx = g >> 3;          // idx in [0,128)
    const int bh  = xcd * 8 + (idx >> 4);         // [0,64): 8 bh per XCD
    const int qblk = idx & 15;                    // q-block [0,16)
    const int b = bh >> 4, h = bh & 15;
    const int tid = threadIdx.x, wid = tid >> 6, lane = tid & 63;
    const int l16 = lane & 15, quad = lane >> 4;
    const bf16* Qbh = Q  + (size_t)bh * Ss * HDd;
    const bf16* Kbh = Kp + (size_t)bh * Tt * HDd;
    const bf16* Vbh = Vt + (size_t)bh * HDd * Tt;
    const int*  mb  = mask + (size_t)b * Ss * Tt;  // mb[t] = mask[b,0,t]
    const int q0 = qblk * 64 + wid * 16;
    bf16* Psw = &Ps[wid][0];

    // Q fragments (A-layout): rows q0+l16, k halves [0,32) and [32,64)
    const bf16x8 qf0 = *(const bf16x8*)(Qbh + (size_t)(q0 + l16) * HDd + quad * 8);
    const bf16x8 qf1 = *(const bf16x8*)(Qbh + (size_t)(q0 + l16) * HDd + 32 + quad * 8);

    float ls[4];
    f32x4 o[4];
    const f32x4 z4 = {0.f, 0.f, 0.f, 0.f};
#pragma unroll
    for (int r = 0; r < 4; r++) ls[r] = 0.f;
#pragma unroll
    for (int dblk = 0; dblk < 4; dblk++) o[dblk] = z4;

    // staging lane decomposition: 8 lanes per 64-elem (128B) row
    const int srow = lane >> 3;          // 0..7: row within an 8-row chunk
    const int schk = lane & 7;           // 0..7: 16B chunk within the row
    const int sswz = (schk ^ srow) * 8;  // swizzled source element offset
    const int c80 = wid * 2, c81 = wid * 2 + 1;   // this wave's 8-row chunks

    // per-thread global bases (tile offset added per tile) and LDS dests
    const bf16* kg0 = Kbh + (size_t)(c80 * 8 + srow) * HDd + sswz;
    const bf16* kg1 = Kbh + (size_t)(c81 * 8 + srow) * HDd + sswz;
    const bf16* vg0 = Vbh + (size_t)(c80 * 8 + srow) * Tt + sswz;
    const bf16* vg1 = Vbh + (size_t)(c81 * 8 + srow) * Tt + sswz;
    bf16* kd0 = Ks + c80 * 512 + lane * 8;
    bf16* kd1 = Ks + c81 * 512 + lane * 8;
    bf16* vd0 = Vs + c80 * 512 + lane * 8;
    bf16* vd1 = Vs + c81 * 512 + lane * 8;

    bf16x8 ka0, ka1, va0, va1;              // reg buffer A
    bf16x8 kb0, kb1, vb0, vb1;              // reg buffer B
    int mA0, mA1, mA2, mA3, mB0, mB1, mB2, mB3;

#define LOADA(KT) do { const int _kt = (KT);                          \
    ka0 = *(const bf16x8*)(kg0 + (size_t)_kt * HDd);                  \
    ka1 = *(const bf16x8*)(kg1 + (size_t)_kt * HDd);                  \
    va0 = *(const bf16x8*)(vg0 + _kt);                                \
    va1 = *(const bf16x8*)(vg1 + _kt);                                \
    mA0 = mb[_kt + l16];      mA1 = mb[_kt + 16 + l16];               \
    mA2 = mb[_kt + 32 + l16]; mA3 = mb[_kt + 48 + l16]; } while (0)
#define LOADB(KT) do { const int _kt = (KT);                          \
    kb0 = *(const bf16x8*)(kg0 + (size_t)_kt * HDd);                  \
    kb1 = *(const bf16x8*)(kg1 + (size_t)_kt * HDd);                  \
    vb0 = *(const bf16x8*)(vg0 + _kt);                                \
    vb1 = *(const bf16x8*)(vg1 + _kt);                                \
    mB0 = mb[_kt + l16];      mB1 = mb[_kt + 16 + l16];               \
    mB2 = mb[_kt + 32 + l16]; mB3 = mb[_kt + 48 + l16]; } while (0)
#define STOREA() do {                                                 \
    *(bf16x8*)kd0 = ka0; *(bf16x8*)kd1 = ka1;                         \
    *(bf16x8*)vd0 = va0; *(bf16x8*)vd1 = va1; } while (0)
#define STOREB() do {                                                 \
    *(bf16x8*)kd0 = kb0; *(bf16x8*)kd1 = kb1;                         \
    *(bf16x8*)vd0 = vb0; *(bf16x8*)vd1 = vb1; } while (0)

    auto compute = [&](int m0, int m1, int m2, int m3) {
        // QK^T: 4 n-blocks of 16 keys, 2 k-halves of 32 channels
        f32x4 sc[4];
#pragma unroll
        for (int nb = 0; nb < 4; nb++) sc[nb] = z4;
#pragma unroll
        for (int nb = 0; nb < 4; nb++) {
            const bf16* krow = Ks + (nb * 16 + l16) * 64;
            const bf16x8 kf0 = *(const bf16x8*)(krow + ((quad       ^ (l16 & 7)) * 8));
            const bf16x8 kf1 = *(const bf16x8*)(krow + (((4 + quad) ^ (l16 & 7)) * 8));
            sc[nb] = __builtin_amdgcn_mfma_f32_16x16x32_bf16(qf0, kf0, sc[nb], 0, 0, 0);
            sc[nb] = __builtin_amdgcn_mfma_f32_16x16x32_bf16(qf1, kf1, sc[nb], 0, 0, 0);
        }

        // softmax numerator (no max subtraction) + P store (C->A layout)
        const int mm[4] = {m0, m1, m2, m3};
#pragma unroll
        for (int nb = 0; nb < 4; nb++) {
            const float madd = mm[nb] ? 0.f : -1e30f;
#pragma unroll
            for (int r = 0; r < 4; r++) {
                const float p = __expf(sc[nb][r] * 0.125f + madd);
                ls[r] += p;
                Psw[(quad * 4 + r) * 72 + nb * 16 + l16] = (bf16)p;
            }
        }

        // O += P @ V : A = P (rows q), B = V^T (rows d), k = t in 2 halves
#pragma unroll
        for (int kh = 0; kh < 2; kh++) {
            const bf16x8 pf = *(const bf16x8*)(Psw + l16 * 72 + kh * 32 + quad * 8);
#pragma unroll
            for (int dblk = 0; dblk < 4; dblk++) {
                const bf16x8 vf = *(const bf16x8*)(Vs + (dblk * 16 + l16) * 64 +
                                                   (((kh * 4 + quad) ^ (l16 & 7)) * 8));
                o[dblk] = __builtin_amdgcn_mfma_f32_16x16x32_bf16(pf, vf, o[dblk], 0, 0, 0);
            }
        }
    };

    // prologue: tile 0 into reg buffer A
    LOADA(0);

    for (int kt = 0; kt < Tt; kt += 128) {
        // ---- tile kt (regs A) ----
        BARRIER_LDS();                 // all waves done reading prev tile's LDS
        LOADB(kt + 64);                // prefetch next tile (kt+64 <= 960 always)
        STOREA();                      // compiler waits vmcnt(N) for A regs only
        BARRIER_LDS();                 // ds_writes visible to all waves
        compute(mA0, mA1, mA2, mA3);

        // ---- tile kt+64 (regs B) ----
        BARRIER_LDS();
        LOADA((kt + 128 < Tt) ? (kt + 128) : (Tt - 64));  // last one redundant
        STOREB();
        BARRIER_LDS();
        compute(mB0, mB1, mB2, mB3);
    }
#undef LOADA
#undef LOADB
#undef STOREA
#undef STOREB

    // row sums: reduce ls across the 16 l16 lanes
#pragma unroll
    for (int off = 1; off <= 8; off <<= 1)
#pragma unroll
        for (int r = 0; r < 4; r++)
            ls[r] += __shfl_xor(ls[r], off, 64);
    float inv[4];
#pragma unroll
    for (int r = 0; r < 4; r++) inv[r] = 1.f / ls[r];

#pragma unroll
    for (int dblk = 0; dblk < 4; dblk++) {
#pragma unroll
        for (int r = 0; r < 4; r++) {
            const int srow_q = q0 + quad * 4 + r;
            const int d = dblk * 16 + l16;
            X[(size_t)(b * Ss + srow_q) * Cc + h * HDd + d] = (bf16)(o[dblk][r] * inv[r]);
        }
    }
}

// ---------------------------------------------------------------------------
extern "C" void kernel_launch(void* const* d_in, const int* in_sizes, int n_in,
                              void* d_out, int out_size, void* d_ws, size_t ws_size,
                              hipStream_t stream)
{
    const float* query = (const float*)d_in[0];
    const float* key   = (const float*)d_in[1];
    const float* value = (const float*)d_in[2];
    const int*   mask  = (const int*)d_in[3];
    const float* Wq = (const float*)d_in[4];
    const float* bq = (const float*)d_in[5];
    const float* Wk = (const float*)d_in[6];
    const float* bk = (const float*)d_in[7];
    const float* Wv = (const float*)d_in[8];
    const float* bv = (const float*)d_in[9];
    const float* Wo = (const float*)d_in[10];
    const float* bo = (const float*)d_in[11];
    float* out = (float*)d_out;

    char* ws = (char*)d_ws;
    const size_t MB = 1024 * 1024;
    bf16* qb  = (bf16*)(ws + 0 * MB);
    bf16* kb  = (bf16*)(ws + 8 * MB);
    bf16* vb  = (bf16*)(ws + 16 * MB);
    bf16* wqb = (bf16*)(ws + 24 * MB);
    bf16* wkb = (bf16*)(ws + 26 * MB);
    bf16* wvb = (bf16*)(ws + 28 * MB);
    bf16* wob = (bf16*)(ws + 30 * MB);
    bf16* Qp  = (bf16*)(ws + 32 * MB);   // (B,H,S,HD) bf16
    bf16* Kpp = (bf16*)(ws + 40 * MB);   // (B,H,T,HD) bf16
    bf16* Vtp = (bf16*)(ws + 48 * MB);   // (B,H,HD,T) bf16
    bf16* Xb  = (bf16*)(ws + 56 * MB);   // attn out (B*S, C) bf16

    cvt8<<<dim3(2048, 7), 256, 0, stream>>>(query, key, value, Wq, Wk, Wv, Wo,
                                            qb, kb, vb, wqb, wkb, wvb, wob);
    gemm_qkv<<<dim3(32, 16, 3), 256, 0, stream>>>(qb, kb, vb, wqb, wkb, wvb,
                                                  bq, bk, bv, Qp, Kpp, Vtp);
    attn<<<dim3(1024), 256, 0, stream>>>(Qp, Kpp, Vtp, mask, Xb);
    gemm_out<<<dim3(32, 16), 256, 0, stream>>>(Xb, wob, bo, mask, out);
}

// Round 3
// 223.068 us; speedup vs baseline: 1.0454x; 1.0425x over previous
//
#include <hip/hip_runtime.h>
#include <stdint.h>

// Problem dims (fixed by reference)
#define Bb  4
#define Ss  1024
#define Tt  1024
#define Cc  1024
#define Hh  16
#define HDd 64
#define Kk  1024   // inner dim for all projections (QIN=CTX=C=1024)

typedef __bf16 bf16;
typedef __bf16 bf16x8 __attribute__((ext_vector_type(8)));
typedef float  f32x4  __attribute__((ext_vector_type(4)));
typedef __attribute__((address_space(1))) uint32_t gu32;
typedef __attribute__((address_space(3))) uint32_t lu32;

// async global->LDS, 16B per lane; LDS dest = wave-uniform base + lane*16
__device__ __forceinline__ void load_lds16(const bf16* g, bf16* l) {
    __builtin_amdgcn_global_load_lds((gu32*)g, (lu32*)l, 16, 0, 0);
}

// raw barrier with LDS-only drain: does NOT force vmcnt(0), so global
// prefetch loads stay in flight across it (counted-vmcnt pipelining).
#define BARRIER_LDS() do {                                    \
    asm volatile("s_waitcnt lgkmcnt(0)" ::: "memory");        \
    __builtin_amdgcn_s_barrier();                             \
} while (0)

// full drain barrier (global staging complete)
#define BARRIER_VM() do {                                     \
    asm volatile("s_waitcnt vmcnt(0)" ::: "memory");          \
    __builtin_amdgcn_s_barrier();                             \
} while (0)

// ---------------------------------------------------------------------------
// fp32 -> bf16 convert, 8 elems/thread; 7 tensors via blockIdx.y
// ---------------------------------------------------------------------------
__global__ void cvt8(const float* __restrict__ s0, const float* __restrict__ s1,
                     const float* __restrict__ s2, const float* __restrict__ s3,
                     const float* __restrict__ s4, const float* __restrict__ s5,
                     const float* __restrict__ s6,
                     bf16* __restrict__ d0, bf16* __restrict__ d1,
                     bf16* __restrict__ d2, bf16* __restrict__ d3,
                     bf16* __restrict__ d4, bf16* __restrict__ d5,
                     bf16* __restrict__ d6)
{
    const float* s; bf16* d; int n;
    switch (blockIdx.y) {
        case 0: s = s0; d = d0; n = Bb * Ss * Kk; break;
        case 1: s = s1; d = d1; n = Bb * Ss * Kk; break;
        case 2: s = s2; d = d2; n = Bb * Ss * Kk; break;
        case 3: s = s3; d = d3; n = Cc * Kk; break;
        case 4: s = s4; d = d4; n = Cc * Kk; break;
        case 5: s = s5; d = d5; n = Cc * Kk; break;
        default: s = s6; d = d6; n = Cc * Kk; break;
    }
    const int i = (blockIdx.x * blockDim.x + threadIdx.x) * 8;
    if (i >= n) return;
    const float4 a = *(const float4*)(s + i);
    const float4 c = *(const float4*)(s + i + 4);
    bf16x8 o;
    o[0] = (bf16)a.x; o[1] = (bf16)a.y; o[2] = (bf16)a.z; o[3] = (bf16)a.w;
    o[4] = (bf16)c.x; o[5] = (bf16)c.y; o[6] = (bf16)c.z; o[7] = (bf16)c.w;
    *(bf16x8*)(d + i) = o;
}

// ---------------------------------------------------------------------------
// NT-GEMM mainloop, 128x64 C-tile, BK=64, XOR-swizzled LDS (chunk ^ row&7).
// SINGLE-buffered 24 KB LDS (R2's 48 KB dbuf REGRESSED: blocks/CU 6->3 ate
// the TLP that was hiding latency; do not re-add LDS double-buffering).
//
// REG-FRAGMENT PREFETCH: per k-step, read ALL 12 fragments (both k-halves)
// into registers, barrier (lgkm only), then issue the NEXT tile's
// global_load_lds into the SAME buffer while the 32 MFMAs run from regs,
// then vmcnt(0)+barrier. Same 2 barriers/k-step as the naive loop, but the
// vmcnt drain lands ~160+ cyc after load issue instead of ~0.
//
// NOTE: natural blockIdx mapping kept deliberately — default round-robin
// (f%8 = XCD) gives each XCD a FIXED set of A-tiles (L2-resident) x all
// W-tiles (resident). Round-7's yy-grouping remap thrashed A
// (FETCH 37 -> 104 MB). Do not "optimize" the grid mapping here again.
// ---------------------------------------------------------------------------
__device__ __forceinline__ void mainloop_128x64_pf(
    const bf16* __restrict__ Ab, const bf16* __restrict__ Wb,
    bf16* As, bf16* Bs, f32x4 acc[4][2])
{
    const int tid  = threadIdx.x;
    const int wid  = tid >> 6;
    const int lane = tid & 63;
    const int l16  = lane & 15;
    const int quad = lane >> 4;
    const int wm   = wid >> 1;
    const int wn   = wid & 1;
    const int r8   = lane >> 3;              // row within 8-row staging chunk
    const int ssw  = ((lane & 7) ^ r8) * 8;  // swizzled k-chunk (elems)

    auto stage = [&](int k0) {
#pragma unroll
        for (int p = 0; p < 4; p++) {        // A: 128 rows
            const int rb = wid * 32 + p * 8;
            load_lds16(Ab + (size_t)(rb + r8) * Kk + k0 + ssw, As + rb * 64);
        }
#pragma unroll
        for (int p = 0; p < 2; p++) {        // B: 64 rows
            const int rb = wid * 16 + p * 8;
            load_lds16(Wb + (size_t)(rb + r8) * Kk + k0 + ssw, Bs + rb * 64);
        }
    };

    // prologue: tile 0 staged and drained
    stage(0);
    BARRIER_VM();

    for (int k0 = 0; k0 < Kk; k0 += 64) {
        // 1) all fragments for this tile -> regs (12 x ds_read_b128)
        bf16x8 af[2][4], bw[2][2];
#pragma unroll
        for (int kh = 0; kh < 2; kh++) {
#pragma unroll
            for (int i = 0; i < 4; i++)
                af[kh][i] = *(const bf16x8*)(As + (wm * 64 + i * 16 + l16) * 64 +
                                             (((kh * 4 + quad) ^ (l16 & 7)) * 8));
#pragma unroll
            for (int j = 0; j < 2; j++)
                bw[kh][j] = *(const bf16x8*)(Bs + (wn * 32 + j * 16 + l16) * 64 +
                                             (((kh * 4 + quad) ^ (l16 & 7)) * 8));
        }
        // 2) all waves finished READING the LDS tile
        BARRIER_LDS();
        // 3) next tile's async loads fly under the MFMAs below
        if (k0 + 64 < Kk) stage(k0 + 64);
        // 4) 32 MFMAs from registers
#pragma unroll
        for (int kh = 0; kh < 2; kh++)
#pragma unroll
            for (int i = 0; i < 4; i++)
#pragma unroll
                for (int j = 0; j < 2; j++)
                    acc[i][j] = __builtin_amdgcn_mfma_f32_16x16x32_bf16(af[kh][i], bw[kh][j], acc[i][j], 0, 0, 0);
        // 5) staging complete before next iteration reads it
        BARRIER_VM();
    }
}

// QKV projections: z selects {Q,K,V}. Q,K -> (B,H,S,HD); V -> (B,H,HD,T)
// Tile 128x64, grid (32, 16, 3) = 1536 blocks. Natural mapping.
__global__ __launch_bounds__(256)
void gemm_qkv(const bf16* __restrict__ Aq, const bf16* __restrict__ Ak, const bf16* __restrict__ Av,
              const bf16* __restrict__ Wq, const bf16* __restrict__ Wk, const bf16* __restrict__ Wv,
              const float* __restrict__ bq, const float* __restrict__ bk, const float* __restrict__ bv,
              bf16* __restrict__ Oq, bf16* __restrict__ Ok, bf16* __restrict__ Ov)
{
    __shared__ __align__(16) bf16 As[128 * 64];   // 16 KB (single buffer)
    __shared__ __align__(16) bf16 Bs[64 * 64];    // 8 KB
    const int z = blockIdx.z;
    const bf16*  A    = (z == 0) ? Aq : (z == 1) ? Ak : Av;
    const bf16*  W    = (z == 0) ? Wq : (z == 1) ? Wk : Wv;
    const float* bias = (z == 0) ? bq : (z == 1) ? bk : bv;
    bf16*        O    = (z == 0) ? Oq : (z == 1) ? Ok : Ov;

    f32x4 acc[4][2];
    const f32x4 z4 = {0.f, 0.f, 0.f, 0.f};
#pragma unroll
    for (int i = 0; i < 4; i++)
#pragma unroll
        for (int j = 0; j < 2; j++) acc[i][j] = z4;

    mainloop_128x64_pf(A + (size_t)blockIdx.x * 128 * Kk,
                       W + (size_t)blockIdx.y * 64 * Kk, As, Bs, acc);

    const int tid = threadIdx.x;
    const int wid = tid >> 6, lane = tid & 63;
    const int l16 = lane & 15, quad = lane >> 4;
    const int wm = wid >> 1, wn = wid & 1;
    const int row0 = blockIdx.x * 128 + wm * 64;
    const int col0 = blockIdx.y * 64 + wn * 32;
#pragma unroll
    for (int j = 0; j < 2; j++) {
        const int col = col0 + j * 16 + l16;     // c = h*64 + d
        const float bj = bias[col];
        const int h = col >> 6, d = col & 63;
#pragma unroll
        for (int i = 0; i < 4; i++) {
#pragma unroll
            for (int r = 0; r < 4; r++) {
                const int row = row0 + i * 16 + quad * 4 + r;  // row = b*S + s
                const int b = row >> 10, s = row & 1023;
                const bf16 val = (bf16)(acc[i][j][r] + bj);
                if (z == 2) {
                    Ov[((size_t)((b * Hh + h) * HDd + d)) * Tt + s] = val;  // V^T
                } else {
                    O[((size_t)(b * Hh + h) * Ss + s) * HDd + d] = val;
                }
            }
        }
    }
}

// Output projection: 128x64 tile, grid (32, 16) = 512 blocks.
// Natural mapping. fp32 out, + bias, * rowmask (mask[b,s,0])
__global__ __launch_bounds__(256)
void gemm_out(const bf16* __restrict__ A, const bf16* __restrict__ W,
              const float* __restrict__ bias, const int* __restrict__ mask,
              float* __restrict__ out)
{
    __shared__ __align__(16) bf16 As[128 * 64];   // 16 KB
    __shared__ __align__(16) bf16 Bs[64 * 64];    // 8 KB
    f32x4 acc[4][2];
    const f32x4 z4 = {0.f, 0.f, 0.f, 0.f};
#pragma unroll
    for (int i = 0; i < 4; i++)
#pragma unroll
        for (int j = 0; j < 2; j++) acc[i][j] = z4;

    mainloop_128x64_pf(A + (size_t)blockIdx.x * 128 * Kk,
                       W + (size_t)blockIdx.y * 64 * Kk, As, Bs, acc);

    const int tid = threadIdx.x;
    const int wid = tid >> 6, lane = tid & 63;
    const int l16 = lane & 15, quad = lane >> 4;
    const int wm = wid >> 1, wn = wid & 1;
    const int row0 = blockIdx.x * 128 + wm * 64;
    const int col0 = blockIdx.y * 64 + wn * 32;
#pragma unroll
    for (int j = 0; j < 2; j++) {
        const int col = col0 + j * 16 + l16;
        const float bj = bias[col];
#pragma unroll
        for (int i = 0; i < 4; i++) {
#pragma unroll
            for (int r = 0; r < 4; r++) {
                const int row = row0 + i * 16 + quad * 4 + r;
                const float mval = (mask[(size_t)row * Tt] != 0) ? 1.f : 0.f;
                out[(size_t)row * Cc + col] = (acc[i][j][r] + bj) * mval;
            }
        }
    }
}

// ---------------------------------------------------------------------------
// Flash attention v2 + XCD swizzle (KEEP): flat grid 1024; all 16 q-blocks of
// one (b,h) land on the same XCD so K/V (256 KB per bh) stays L2-resident.
//
// Pipelined staging (T14 async-STAGE): K/V tiles go global->reg->LDS with the
// NEXT tile's loads (and its mask dwords) issued before the CURRENT tile's
// compute. Barriers are raw s_barrier + lgkmcnt(0) only — __syncthreads would
// emit s_waitcnt vmcnt(0) and drain the prefetch. Same LDS layout/swizzle as
// before; ds_write_b128 per lane is linear -> conflict-free.
// ---------------------------------------------------------------------------
__global__ __launch_bounds__(256, 4)
void attn(const bf16* __restrict__ Q, const bf16* __restrict__ Kp, const bf16* __restrict__ Vt,
          const int* __restrict__ mask, bf16* __restrict__ X)
{
    __shared__ __align__(16) bf16 Ks[64 * 64];    // [t_local][d]  (swizzled)
    __shared__ __align__(16) bf16 Vs[64 * 64];    // [d][t_local]  (swizzled)
    __shared__ __align__(16) bf16 Ps[4][16 * 72]; // per-wave P, row stride 72
    const int g   = blockIdx.x;
    const int xcd = g & 7, idx = g >> 3;          // idx in [0,128)
    const int bh  = xcd * 8 + (idx >> 4);         // [0,64): 8 bh per XCD
    const int qblk = idx & 15;                    // q-block [0,16)
    const int b = bh >> 4, h = bh & 15;
    const int tid = threadIdx.x, wid = tid >> 6, lane = tid & 63;
    const int l16 = lane & 15, quad = lane >> 4;
    const bf16* Qbh = Q  + (size_t)bh * Ss * HDd;
    const bf16* Kbh = Kp + (size_t)bh * Tt * HDd;
    const bf16* Vbh = Vt + (size_t)bh * HDd * Tt;
    const int*  mb  = mask + (size_t)b * Ss * Tt;  // mb[t] = mask[b,0,t]
    const int q0 = qblk * 64 + wid * 16;
    bf16* Psw = &Ps[wid][0];

    // Q fragments (A-layout): rows q0+l16, k halves [0,32) and [32,64)
    const bf16x8 qf0 = *(const bf16x8*)(Qbh + (size_t)(q0 + l16) * HDd + quad * 8);
    const bf16x8 qf1 = *(const bf16x8*)(Qbh + (size_t)(q0 + l16) * HDd + 32 + quad * 8);

    float ls[4];
    f32x4 o[4];
    const f32x4 z4 = {0.f, 0.f, 0.f, 0.f};
#pragma unroll
    for (int r = 0; r < 4; r++) ls[r] = 0.f;
#pragma unroll
    for (int dblk = 0; dblk < 4; dblk++) o[dblk] = z4;

    // staging lane decomposition: 8 lanes per 64-elem (128B) row
    const int srow = lane >> 3;          // 0..7: row within an 8-row chunk
    const int schk = lane & 7;           // 0..7: 16B chunk within the row
    const int sswz = (schk ^ srow) * 8;  // swizzled source element offset
    const int c80 = wid * 2, c81 = wid * 2 + 1;   // this wave's 8-row chunks

    // per-thread global bases (tile offset added per tile) and LDS dests
    const bf16* kg0 = Kbh + (size_t)(c80 * 8 + srow) * HDd + sswz;
    const bf16* kg1 = Kbh + (size_t)(c81 * 8 + srow) * HDd + sswz;
    const bf16* vg0 = Vbh + (size_t)(c80 * 8 + srow) * Tt + sswz;
    const bf16* vg1 = Vbh + (size_t)(c81 * 8 + srow) * Tt + sswz;
    bf16* kd0 = Ks + c80 * 512 + lane * 8;
    bf16* kd1 = Ks + c81 * 512 + lane * 8;
    bf16* vd0 = Vs + c80 * 512 + lane * 8;
    bf16* vd1 = Vs + c81 * 512 + lane * 8;

    bf16x8 ka0, ka1, va0, va1;              // reg buffer A
    bf16x8 kb0, kb1, vb0, vb1;              // reg buffer B
    int mA0, mA1, mA2, mA3, mB0, mB1, mB2, mB3;

#define LOADA(KT) do { const int _kt = (KT);                          \
    ka0 = *(const bf16x8*)(kg0 + (size_t)_kt * HDd);                  \
    ka1 = *(const bf16x8*)(kg1 + (size_t)_kt * HDd);                  \
    va0 = *(const bf16x8*)(vg0 + _kt);                                \
    va1 = *(const bf16x8*)(vg1 + _kt);                                \
    mA0 = mb[_kt + l16];      mA1 = mb[_kt + 16 + l16];               \
    mA2 = mb[_kt + 32 + l16]; mA3 = mb[_kt + 48 + l16]; } while (0)
#define LOADB(KT) do { const int _kt = (KT);                          \
    kb0 = *(const bf16x8*)(kg0 + (size_t)_kt * HDd);                  \
    kb1 = *(const bf16x8*)(kg1 + (size_t)_kt * HDd);                  \
    vb0 = *(const bf16x8*)(vg0 + _kt);                                \
    vb1 = *(const bf16x8*)(vg1 + _kt);                                \
    mB0 = mb[_kt + l16];      mB1 = mb[_kt + 16 + l16];               \
    mB2 = mb[_kt + 32 + l16]; mB3 = mb[_kt + 48 + l16]; } while (0)
#define STOREA() do {                                                 \
    *(bf16x8*)kd0 = ka0; *(bf16x8*)kd1 = ka1;                         \
    *(bf16x8*)vd0 = va0; *(bf16x8*)vd1 = va1; } while (0)
#define STOREB() do {                                                 \
    *(bf16x8*)kd0 = kb0; *(bf16x8*)kd1 = kb1;                         \
    *(bf16x8*)vd0 = vb0; *(bf16x8*)vd1 = vb1; } while (0)

    auto compute = [&](int m0, int m1, int m2, int m3) {
        // QK^T: 4 n-blocks of 16 keys, 2 k-halves of 32 channels
        f32x4 sc[4];
#pragma unroll
        for (int nb = 0; nb < 4; nb++) sc[nb] = z4;
#pragma unroll
        for (int nb = 0; nb < 4; nb++) {
            const bf16* krow = Ks + (nb * 16 + l16) * 64;
            const bf16x8 kf0 = *(const bf16x8*)(krow + ((quad       ^ (l16 & 7)) * 8));
            const bf16x8 kf1 = *(const bf16x8*)(krow + (((4 + quad) ^ (l16 & 7)) * 8));
            sc[nb] = __builtin_amdgcn_mfma_f32_16x16x32_bf16(qf0, kf0, sc[nb], 0, 0, 0);
            sc[nb] = __builtin_amdgcn_mfma_f32_16x16x32_bf16(qf1, kf1, sc[nb], 0, 0, 0);
        }

        // softmax numerator (no max subtraction) + P store (C->A layout)
        const int mm[4] = {m0, m1, m2, m3};
#pragma unroll
        for (int nb = 0; nb < 4; nb++) {
            const float madd = mm[nb] ? 0.f : -1e30f;
#pragma unroll
            for (int r = 0; r < 4; r++) {
                const float p = __expf(sc[nb][r] * 0.125f + madd);
                ls[r] += p;
                Psw[(quad * 4 + r) * 72 + nb * 16 + l16] = (bf16)p;
            }
        }

        // O += P @ V : A = P (rows q), B = V^T (rows d), k = t in 2 halves
#pragma unroll
        for (int kh = 0; kh < 2; kh++) {
            const bf16x8 pf = *(const bf16x8*)(Psw + l16 * 72 + kh * 32 + quad * 8);
#pragma unroll
            for (int dblk = 0; dblk < 4; dblk++) {
                const bf16x8 vf = *(const bf16x8*)(Vs + (dblk * 16 + l16) * 64 +
                                                   (((kh * 4 + quad) ^ (l16 & 7)) * 8));
                o[dblk] = __builtin_amdgcn_mfma_f32_16x16x32_bf16(pf, vf, o[dblk], 0, 0, 0);
            }
        }
    };

    // prologue: tile 0 into reg buffer A
    LOADA(0);

    for (int kt = 0; kt < Tt; kt += 128) {
        // ---- tile kt (regs A) ----
        BARRIER_LDS();                 // all waves done reading prev tile's LDS
        LOADB(kt + 64);                // prefetch next tile (kt+64 <= 960 always)
        STOREA();                      // compiler waits vmcnt(N) for A regs only
        BARRIER_LDS();                 // ds_writes visible to all waves
        compute(mA0, mA1, mA2, mA3);

        // ---- tile kt+64 (regs B) ----
        BARRIER_LDS();
        LOADA((kt + 128 < Tt) ? (kt + 128) : (Tt - 64));  // last one redundant
        STOREB();
        BARRIER_LDS();
        compute(mB0, mB1, mB2, mB3);
    }
#undef LOADA
#undef LOADB
#undef STOREA
#undef STOREB

    // row sums: reduce ls across the 16 l16 lanes
#pragma unroll
    for (int off = 1; off <= 8; off <<= 1)
#pragma unroll
        for (int r = 0; r < 4; r++)
            ls[r] += __shfl_xor(ls[r], off, 64);
    float inv[4];
#pragma unroll
    for (int r = 0; r < 4; r++) inv[r] = 1.f / ls[r];

#pragma unroll
    for (int dblk = 0; dblk < 4; dblk++) {
#pragma unroll
        for (int r = 0; r < 4; r++) {
            const int srow_q = q0 + quad * 4 + r;
            const int d = dblk * 16 + l16;
            X[(size_t)(b * Ss + srow_q) * Cc + h * HDd + d] = (bf16)(o[dblk][r] * inv[r]);
        }
    }
}

// ---------------------------------------------------------------------------
extern "C" void kernel_launch(void* const* d_in, const int* in_sizes, int n_in,
                              void* d_out, int out_size, void* d_ws, size_t ws_size,
                              hipStream_t stream)
{
    const float* query = (const float*)d_in[0];
    const float* key   = (const float*)d_in[1];
    const float* value = (const float*)d_in[2];
    const int*   mask  = (const int*)d_in[3];
    const float* Wq = (const float*)d_in[4];
    const float* bq = (const float*)d_in[5];
    const float* Wk = (const float*)d_in[6];
    const float* bk = (const float*)d_in[7];
    const float* Wv = (const float*)d_in[8];
    const float* bv = (const float*)d_in[9];
    const float* Wo = (const float*)d_in[10];
    const float* bo = (const float*)d_in[11];
    float* out = (float*)d_out;

    char* ws = (char*)d_ws;
    const size_t MB = 1024 * 1024;
    bf16* qb  = (bf16*)(ws + 0 * MB);
    bf16* kb  = (bf16*)(ws + 8 * MB);
    bf16* vb  = (bf16*)(ws + 16 * MB);
    bf16* wqb = (bf16*)(ws + 24 * MB);
    bf16* wkb = (bf16*)(ws + 26 * MB);
    bf16* wvb = (bf16*)(ws + 28 * MB);
    bf16* wob = (bf16*)(ws + 30 * MB);
    bf16* Qp  = (bf16*)(ws + 32 * MB);   // (B,H,S,HD) bf16
    bf16* Kpp = (bf16*)(ws + 40 * MB);   // (B,H,T,HD) bf16
    bf16* Vtp = (bf16*)(ws + 48 * MB);   // (B,H,HD,T) bf16
    bf16* Xb  = (bf16*)(ws + 56 * MB);   // attn out (B*S, C) bf16

    cvt8<<<dim3(2048, 7), 256, 0, stream>>>(query, key, value, Wq, Wk, Wv, Wo,
                                            qb, kb, vb, wqb, wkb, wvb, wob);
    gemm_qkv<<<dim3(32, 16, 3), 256, 0, stream>>>(qb, kb, vb, wqb, wkb, wvb,
                                                  bq, bk, bv, Qp, Kpp, Vtp);
    attn<<<dim3(1024), 256, 0, stream>>>(Qp, Kpp, Vtp, mask, Xb);
    gemm_out<<<dim3(32, 16), 256, 0, stream>>>(Xb, wob, bo, mask, out);
}

// Round 4
// 221.067 us; speedup vs baseline: 1.0548x; 1.0091x over previous
//
#include <hip/hip_runtime.h>
#include <stdint.h>

// Problem dims (fixed by reference)
#define Bb  4
#define Ss  1024
#define Tt  1024
#define Cc  1024
#define Hh  16
#define HDd 64
#define Kk  1024   // inner dim for all projections (QIN=CTX=C=1024)

typedef __bf16 bf16;
typedef __bf16 bf16x8 __attribute__((ext_vector_type(8)));
typedef float  f32x4  __attribute__((ext_vector_type(4)));
typedef __attribute__((address_space(1))) uint32_t gu32;
typedef __attribute__((address_space(3))) uint32_t lu32;

// async global->LDS, 16B per lane; LDS dest = wave-uniform base + lane*16
__device__ __forceinline__ void load_lds16(const bf16* g, bf16* l) {
    __builtin_amdgcn_global_load_lds((gu32*)g, (lu32*)l, 16, 0, 0);
}

// raw barrier with LDS-only drain: does NOT force vmcnt(0), so global
// prefetch loads stay in flight across it (counted-vmcnt pipelining).
#define BARRIER_LDS() do {                                    \
    asm volatile("s_waitcnt lgkmcnt(0)" ::: "memory");        \
    __builtin_amdgcn_s_barrier();                             \
} while (0)

// full drain barrier (global staging complete)
#define BARRIER_VM() do {                                     \
    asm volatile("s_waitcnt vmcnt(0)" ::: "memory");          \
    __builtin_amdgcn_s_barrier();                             \
} while (0)

// ---------------------------------------------------------------------------
// fp32 -> bf16 convert, 8 elems/thread; 7 tensors via blockIdx.y
// ---------------------------------------------------------------------------
__global__ void cvt8(const float* __restrict__ s0, const float* __restrict__ s1,
                     const float* __restrict__ s2, const float* __restrict__ s3,
                     const float* __restrict__ s4, const float* __restrict__ s5,
                     const float* __restrict__ s6,
                     bf16* __restrict__ d0, bf16* __restrict__ d1,
                     bf16* __restrict__ d2, bf16* __restrict__ d3,
                     bf16* __restrict__ d4, bf16* __restrict__ d5,
                     bf16* __restrict__ d6)
{
    const float* s; bf16* d; int n;
    switch (blockIdx.y) {
        case 0: s = s0; d = d0; n = Bb * Ss * Kk; break;
        case 1: s = s1; d = d1; n = Bb * Ss * Kk; break;
        case 2: s = s2; d = d2; n = Bb * Ss * Kk; break;
        case 3: s = s3; d = d3; n = Cc * Kk; break;
        case 4: s = s4; d = d4; n = Cc * Kk; break;
        case 5: s = s5; d = d5; n = Cc * Kk; break;
        default: s = s6; d = d6; n = Cc * Kk; break;
    }
    const int i = (blockIdx.x * blockDim.x + threadIdx.x) * 8;
    if (i >= n) return;
    const float4 a = *(const float4*)(s + i);
    const float4 c = *(const float4*)(s + i + 4);
    bf16x8 o;
    o[0] = (bf16)a.x; o[1] = (bf16)a.y; o[2] = (bf16)a.z; o[3] = (bf16)a.w;
    o[4] = (bf16)c.x; o[5] = (bf16)c.y; o[6] = (bf16)c.z; o[7] = (bf16)c.w;
    *(bf16x8*)(d + i) = o;
}

// ---------------------------------------------------------------------------
// NT-GEMM mainloop, 128x64 C-tile, BK=64, XOR-swizzled LDS (chunk ^ row&7).
// SINGLE-buffered 24 KB LDS (R2's 48 KB dbuf REGRESSED: blocks/CU 6->3 ate
// the TLP that was hiding latency; R1's 128x128 tile also REGRESSED via
// occupancy collapse. This 128x64 + reg-fragment-prefetch structure is the
// best of three measured variants — a local plateau at ~49 us / 19% MfmaUtil.
// Do not re-try dbuf or bigger tiles with this sync structure.)
//
// REG-FRAGMENT PREFETCH: per k-step, read ALL 12 fragments (both k-halves)
// into registers, barrier (lgkm only), then issue the NEXT tile's
// global_load_lds into the SAME buffer while the MFMAs run from regs,
// then vmcnt(0)+barrier.
//
// NOTE: natural blockIdx mapping kept deliberately — default round-robin
// (f%8 = XCD) gives each XCD a FIXED set of A-tiles (L2-resident) x all
// W-tiles (resident). Round-7's yy-grouping remap thrashed A
// (FETCH 37 -> 104 MB). Do not "optimize" the grid mapping here again.
// ---------------------------------------------------------------------------
__device__ __forceinline__ void mainloop_128x64_pf(
    const bf16* __restrict__ Ab, const bf16* __restrict__ Wb,
    bf16* As, bf16* Bs, f32x4 acc[4][2])
{
    const int tid  = threadIdx.x;
    const int wid  = tid >> 6;
    const int lane = tid & 63;
    const int l16  = lane & 15;
    const int quad = lane >> 4;
    const int wm   = wid >> 1;
    const int wn   = wid & 1;
    const int r8   = lane >> 3;              // row within 8-row staging chunk
    const int ssw  = ((lane & 7) ^ r8) * 8;  // swizzled k-chunk (elems)

    auto stage = [&](int k0) {
#pragma unroll
        for (int p = 0; p < 4; p++) {        // A: 128 rows
            const int rb = wid * 32 + p * 8;
            load_lds16(Ab + (size_t)(rb + r8) * Kk + k0 + ssw, As + rb * 64);
        }
#pragma unroll
        for (int p = 0; p < 2; p++) {        // B: 64 rows
            const int rb = wid * 16 + p * 8;
            load_lds16(Wb + (size_t)(rb + r8) * Kk + k0 + ssw, Bs + rb * 64);
        }
    };

    // prologue: tile 0 staged and drained
    stage(0);
    BARRIER_VM();

    for (int k0 = 0; k0 < Kk; k0 += 64) {
        // 1) all fragments for this tile -> regs (12 x ds_read_b128)
        bf16x8 af[2][4], bw[2][2];
#pragma unroll
        for (int kh = 0; kh < 2; kh++) {
#pragma unroll
            for (int i = 0; i < 4; i++)
                af[kh][i] = *(const bf16x8*)(As + (wm * 64 + i * 16 + l16) * 64 +
                                             (((kh * 4 + quad) ^ (l16 & 7)) * 8));
#pragma unroll
            for (int j = 0; j < 2; j++)
                bw[kh][j] = *(const bf16x8*)(Bs + (wn * 32 + j * 16 + l16) * 64 +
                                             (((kh * 4 + quad) ^ (l16 & 7)) * 8));
        }
        // 2) all waves finished READING the LDS tile
        BARRIER_LDS();
        // 3) next tile's async loads fly under the MFMAs below
        if (k0 + 64 < Kk) stage(k0 + 64);
        // 4) MFMAs from registers
#pragma unroll
        for (int kh = 0; kh < 2; kh++)
#pragma unroll
            for (int i = 0; i < 4; i++)
#pragma unroll
                for (int j = 0; j < 2; j++)
                    acc[i][j] = __builtin_amdgcn_mfma_f32_16x16x32_bf16(af[kh][i], bw[kh][j], acc[i][j], 0, 0, 0);
        // 5) staging complete before next iteration reads it
        BARRIER_VM();
    }
}

// QKV projections: z selects {Q,K,V}. Q,K -> (B,H,S,HD); V -> (B,H,HD,T)
// Tile 128x64, grid (32, 16, 3) = 1536 blocks. Natural mapping.
__global__ __launch_bounds__(256)
void gemm_qkv(const bf16* __restrict__ Aq, const bf16* __restrict__ Ak, const bf16* __restrict__ Av,
              const bf16* __restrict__ Wq, const bf16* __restrict__ Wk, const bf16* __restrict__ Wv,
              const float* __restrict__ bq, const float* __restrict__ bk, const float* __restrict__ bv,
              bf16* __restrict__ Oq, bf16* __restrict__ Ok, bf16* __restrict__ Ov)
{
    __shared__ __align__(16) bf16 As[128 * 64];   // 16 KB (single buffer)
    __shared__ __align__(16) bf16 Bs[64 * 64];    // 8 KB
    const int z = blockIdx.z;
    const bf16*  A    = (z == 0) ? Aq : (z == 1) ? Ak : Av;
    const bf16*  W    = (z == 0) ? Wq : (z == 1) ? Wk : Wv;
    const float* bias = (z == 0) ? bq : (z == 1) ? bk : bv;
    bf16*        O    = (z == 0) ? Oq : (z == 1) ? Ok : Ov;

    f32x4 acc[4][2];
    const f32x4 z4 = {0.f, 0.f, 0.f, 0.f};
#pragma unroll
    for (int i = 0; i < 4; i++)
#pragma unroll
        for (int j = 0; j < 2; j++) acc[i][j] = z4;

    mainloop_128x64_pf(A + (size_t)blockIdx.x * 128 * Kk,
                       W + (size_t)blockIdx.y * 64 * Kk, As, Bs, acc);

    const int tid = threadIdx.x;
    const int wid = tid >> 6, lane = tid & 63;
    const int l16 = lane & 15, quad = lane >> 4;
    const int wm = wid >> 1, wn = wid & 1;
    const int row0 = blockIdx.x * 128 + wm * 64;
    const int col0 = blockIdx.y * 64 + wn * 32;
#pragma unroll
    for (int j = 0; j < 2; j++) {
        const int col = col0 + j * 16 + l16;     // c = h*64 + d
        const float bj = bias[col];
        const int h = col >> 6, d = col & 63;
#pragma unroll
        for (int i = 0; i < 4; i++) {
#pragma unroll
            for (int r = 0; r < 4; r++) {
                const int row = row0 + i * 16 + quad * 4 + r;  // row = b*S + s
                const int b = row >> 10, s = row & 1023;
                const bf16 val = (bf16)(acc[i][j][r] + bj);
                if (z == 2) {
                    Ov[((size_t)((b * Hh + h) * HDd + d)) * Tt + s] = val;  // V^T
                } else {
                    O[((size_t)(b * Hh + h) * Ss + s) * HDd + d] = val;
                }
            }
        }
    }
}

// Output projection: 128x64 tile, grid (32, 16) = 512 blocks.
// Natural mapping. fp32 out, + bias, * rowmask (mask[b,s,0])
__global__ __launch_bounds__(256)
void gemm_out(const bf16* __restrict__ A, const bf16* __restrict__ W,
              const float* __restrict__ bias, const int* __restrict__ mask,
              float* __restrict__ out)
{
    __shared__ __align__(16) bf16 As[128 * 64];   // 16 KB
    __shared__ __align__(16) bf16 Bs[64 * 64];    // 8 KB
    f32x4 acc[4][2];
    const f32x4 z4 = {0.f, 0.f, 0.f, 0.f};
#pragma unroll
    for (int i = 0; i < 4; i++)
#pragma unroll
        for (int j = 0; j < 2; j++) acc[i][j] = z4;

    mainloop_128x64_pf(A + (size_t)blockIdx.x * 128 * Kk,
                       W + (size_t)blockIdx.y * 64 * Kk, As, Bs, acc);

    const int tid = threadIdx.x;
    const int wid = tid >> 6, lane = tid & 63;
    const int l16 = lane & 15, quad = lane >> 4;
    const int wm = wid >> 1, wn = wid & 1;
    const int row0 = blockIdx.x * 128 + wm * 64;
    const int col0 = blockIdx.y * 64 + wn * 32;
#pragma unroll
    for (int j = 0; j < 2; j++) {
        const int col = col0 + j * 16 + l16;
        const float bj = bias[col];
#pragma unroll
        for (int i = 0; i < 4; i++) {
#pragma unroll
            for (int r = 0; r < 4; r++) {
                const int row = row0 + i * 16 + quad * 4 + r;
                const float mval = (mask[(size_t)row * Tt] != 0) ? 1.f : 0.f;
                out[(size_t)row * Cc + col] = (acc[i][j][r] + bj) * mval;
            }
        }
    }
}

// ---------------------------------------------------------------------------
// Flash attention v2, QBLK=128 (32 q-rows/wave in 2x16-row groups).
// K/V fragments are loaded ONCE per tile and reused for both q-groups:
// 32 MFMA per tile per wave against the same staging cost as the old
// QBLK=64 version (16 MFMA) — 2x compute:overhead ratio, and half the
// per-(b,h) K/V re-staging (8 q-blocks instead of 16).
// XCD swizzle (KEEP): all 8 q-blocks of one (b,h) land on the same XCD so
// K/V (256 KB per bh) stays L2-resident.
// T14 async staging (KEEP): global->reg->LDS, next tile's loads issued
// before current tile's compute; raw s_barrier + lgkmcnt only.
// ---------------------------------------------------------------------------
__global__ __launch_bounds__(256, 2)
void attn(const bf16* __restrict__ Q, const bf16* __restrict__ Kp, const bf16* __restrict__ Vt,
          const int* __restrict__ mask, bf16* __restrict__ X)
{
    __shared__ __align__(16) bf16 Ks[64 * 64];    // [t_local][d]  (swizzled)
    __shared__ __align__(16) bf16 Vs[64 * 64];    // [d][t_local]  (swizzled)
    __shared__ __align__(16) bf16 Ps[4][32 * 72]; // per-wave P, row stride 72
    const int g   = blockIdx.x;                   // [0,512)
    const int xcd = g & 7, idx = g >> 3;          // idx in [0,64)
    const int bh  = xcd * 8 + (idx >> 3);         // [0,64): 8 bh per XCD
    const int qblk = idx & 7;                     // q-block [0,8), 128 rows
    const int b = bh >> 4, h = bh & 15;
    const int tid = threadIdx.x, wid = tid >> 6, lane = tid & 63;
    const int l16 = lane & 15, quad = lane >> 4;
    const bf16* Qbh = Q  + (size_t)bh * Ss * HDd;
    const bf16* Kbh = Kp + (size_t)bh * Tt * HDd;
    const bf16* Vbh = Vt + (size_t)bh * HDd * Tt;
    const int*  mb  = mask + (size_t)b * Ss * Tt;  // mb[t] = mask[b,0,t]
    const int q0 = qblk * 128 + wid * 32;          // 32 rows per wave
    bf16* Psw = &Ps[wid][0];

    // Q fragments (A-layout): 2 groups of 16 rows, k halves [0,32) and [32,64)
    bf16x8 qf[2][2];
#pragma unroll
    for (int u = 0; u < 2; u++) {
        qf[u][0] = *(const bf16x8*)(Qbh + (size_t)(q0 + u * 16 + l16) * HDd + quad * 8);
        qf[u][1] = *(const bf16x8*)(Qbh + (size_t)(q0 + u * 16 + l16) * HDd + 32 + quad * 8);
    }

    float ls[2][4];
    f32x4 o[2][4];
    const f32x4 z4 = {0.f, 0.f, 0.f, 0.f};
#pragma unroll
    for (int u = 0; u < 2; u++)
#pragma unroll
        for (int r = 0; r < 4; r++) ls[u][r] = 0.f;
#pragma unroll
    for (int u = 0; u < 2; u++)
#pragma unroll
        for (int dblk = 0; dblk < 4; dblk++) o[u][dblk] = z4;

    // staging lane decomposition: 8 lanes per 64-elem (128B) row
    const int srow = lane >> 3;          // 0..7: row within an 8-row chunk
    const int schk = lane & 7;           // 0..7: 16B chunk within the row
    const int sswz = (schk ^ srow) * 8;  // swizzled source element offset
    const int c80 = wid * 2, c81 = wid * 2 + 1;   // this wave's 8-row chunks

    // per-thread global bases (tile offset added per tile) and LDS dests
    const bf16* kg0 = Kbh + (size_t)(c80 * 8 + srow) * HDd + sswz;
    const bf16* kg1 = Kbh + (size_t)(c81 * 8 + srow) * HDd + sswz;
    const bf16* vg0 = Vbh + (size_t)(c80 * 8 + srow) * Tt + sswz;
    const bf16* vg1 = Vbh + (size_t)(c81 * 8 + srow) * Tt + sswz;
    bf16* kd0 = Ks + c80 * 512 + lane * 8;
    bf16* kd1 = Ks + c81 * 512 + lane * 8;
    bf16* vd0 = Vs + c80 * 512 + lane * 8;
    bf16* vd1 = Vs + c81 * 512 + lane * 8;

    bf16x8 ka0, ka1, va0, va1;              // reg buffer A
    bf16x8 kb0, kb1, vb0, vb1;              // reg buffer B
    int mA0, mA1, mA2, mA3, mB0, mB1, mB2, mB3;

#define LOADA(KT) do { const int _kt = (KT);                          \
    ka0 = *(const bf16x8*)(kg0 + (size_t)_kt * HDd);                  \
    ka1 = *(const bf16x8*)(kg1 + (size_t)_kt * HDd);                  \
    va0 = *(const bf16x8*)(vg0 + _kt);                                \
    va1 = *(const bf16x8*)(vg1 + _kt);                                \
    mA0 = mb[_kt + l16];      mA1 = mb[_kt + 16 + l16];               \
    mA2 = mb[_kt + 32 + l16]; mA3 = mb[_kt + 48 + l16]; } while (0)
#define LOADB(KT) do { const int _kt = (KT);                          \
    kb0 = *(const bf16x8*)(kg0 + (size_t)_kt * HDd);                  \
    kb1 = *(const bf16x8*)(kg1 + (size_t)_kt * HDd);                  \
    vb0 = *(const bf16x8*)(vg0 + _kt);                                \
    vb1 = *(const bf16x8*)(vg1 + _kt);                                \
    mB0 = mb[_kt + l16];      mB1 = mb[_kt + 16 + l16];               \
    mB2 = mb[_kt + 32 + l16]; mB3 = mb[_kt + 48 + l16]; } while (0)
#define STOREA() do {                                                 \
    *(bf16x8*)kd0 = ka0; *(bf16x8*)kd1 = ka1;                         \
    *(bf16x8*)vd0 = va0; *(bf16x8*)vd1 = va1; } while (0)
#define STOREB() do {                                                 \
    *(bf16x8*)kd0 = kb0; *(bf16x8*)kd1 = kb1;                         \
    *(bf16x8*)vd0 = vb0; *(bf16x8*)vd1 = vb1; } while (0)

    auto compute = [&](int m0, int m1, int m2, int m3) {
        // QK^T: 4 n-blocks of 16 keys x 2 q-groups, K-frags shared across u
        f32x4 sc[2][4];
#pragma unroll
        for (int u = 0; u < 2; u++)
#pragma unroll
            for (int nb = 0; nb < 4; nb++) sc[u][nb] = z4;
#pragma unroll
        for (int nb = 0; nb < 4; nb++) {
            const bf16* krow = Ks + (nb * 16 + l16) * 64;
            const bf16x8 kf0 = *(const bf16x8*)(krow + ((quad       ^ (l16 & 7)) * 8));
            const bf16x8 kf1 = *(const bf16x8*)(krow + (((4 + quad) ^ (l16 & 7)) * 8));
#pragma unroll
            for (int u = 0; u < 2; u++) {
                sc[u][nb] = __builtin_amdgcn_mfma_f32_16x16x32_bf16(qf[u][0], kf0, sc[u][nb], 0, 0, 0);
                sc[u][nb] = __builtin_amdgcn_mfma_f32_16x16x32_bf16(qf[u][1], kf1, sc[u][nb], 0, 0, 0);
            }
        }

        // softmax numerator (no max subtraction) + P store (C->A layout)
        const int mm[4] = {m0, m1, m2, m3};
#pragma unroll
        for (int nb = 0; nb < 4; nb++) {
            const float madd = mm[nb] ? 0.f : -1e30f;
#pragma unroll
            for (int u = 0; u < 2; u++) {
#pragma unroll
                for (int r = 0; r < 4; r++) {
                    const float p = __expf(sc[u][nb][r] * 0.125f + madd);
                    ls[u][r] += p;
                    Psw[(u * 16 + quad * 4 + r) * 72 + nb * 16 + l16] = (bf16)p;
                }
            }
        }

        // O += P @ V : A = P (rows q), B = V^T (rows d), V-frags shared across u
#pragma unroll
        for (int kh = 0; kh < 2; kh++) {
            const bf16x8 pf0 = *(const bf16x8*)(Psw + (l16) * 72 + kh * 32 + quad * 8);
            const bf16x8 pf1 = *(const bf16x8*)(Psw + (16 + l16) * 72 + kh * 32 + quad * 8);
#pragma unroll
            for (int dblk = 0; dblk < 4; dblk++) {
                const bf16x8 vf = *(const bf16x8*)(Vs + (dblk * 16 + l16) * 64 +
                                                   (((kh * 4 + quad) ^ (l16 & 7)) * 8));
                o[0][dblk] = __builtin_amdgcn_mfma_f32_16x16x32_bf16(pf0, vf, o[0][dblk], 0, 0, 0);
                o[1][dblk] = __builtin_amdgcn_mfma_f32_16x16x32_bf16(pf1, vf, o[1][dblk], 0, 0, 0);
            }
        }
    };

    // prologue: tile 0 into reg buffer A
    LOADA(0);

    for (int kt = 0; kt < Tt; kt += 128) {
        // ---- tile kt (regs A) ----
        BARRIER_LDS();                 // all waves done reading prev tile's LDS
        LOADB(kt + 64);                // prefetch next tile (kt+64 <= 960 always)
        STOREA();                      // compiler waits vmcnt(N) for A regs only
        BARRIER_LDS();                 // ds_writes visible to all waves
        compute(mA0, mA1, mA2, mA3);

        // ---- tile kt+64 (regs B) ----
        BARRIER_LDS();
        LOADA((kt + 128 < Tt) ? (kt + 128) : (Tt - 64));  // last one redundant
        STOREB();
        BARRIER_LDS();
        compute(mB0, mB1, mB2, mB3);
    }
#undef LOADA
#undef LOADB
#undef STOREA
#undef STOREB

    // row sums: reduce ls across the 16 l16 lanes
#pragma unroll
    for (int off = 1; off <= 8; off <<= 1)
#pragma unroll
        for (int u = 0; u < 2; u++)
#pragma unroll
            for (int r = 0; r < 4; r++)
                ls[u][r] += __shfl_xor(ls[u][r], off, 64);
    float inv[2][4];
#pragma unroll
    for (int u = 0; u < 2; u++)
#pragma unroll
        for (int r = 0; r < 4; r++) inv[u][r] = 1.f / ls[u][r];

#pragma unroll
    for (int u = 0; u < 2; u++) {
#pragma unroll
        for (int dblk = 0; dblk < 4; dblk++) {
#pragma unroll
            for (int r = 0; r < 4; r++) {
                const int srow_q = q0 + u * 16 + quad * 4 + r;
                const int d = dblk * 16 + l16;
                X[(size_t)(b * Ss + srow_q) * Cc + h * HDd + d] = (bf16)(o[u][dblk][r] * inv[u][r]);
            }
        }
    }
}

// ---------------------------------------------------------------------------
extern "C" void kernel_launch(void* const* d_in, const int* in_sizes, int n_in,
                              void* d_out, int out_size, void* d_ws, size_t ws_size,
                              hipStream_t stream)
{
    const float* query = (const float*)d_in[0];
    const float* key   = (const float*)d_in[1];
    const float* value = (const float*)d_in[2];
    const int*   mask  = (const int*)d_in[3];
    const float* Wq = (const float*)d_in[4];
    const float* bq = (const float*)d_in[5];
    const float* Wk = (const float*)d_in[6];
    const float* bk = (const float*)d_in[7];
    const float* Wv = (const float*)d_in[8];
    const float* bv = (const float*)d_in[9];
    const float* Wo = (const float*)d_in[10];
    const float* bo = (const float*)d_in[11];
    float* out = (float*)d_out;

    char* ws = (char*)d_ws;
    const size_t MB = 1024 * 1024;
    bf16* qb  = (bf16*)(ws + 0 * MB);
    bf16* kb  = (bf16*)(ws + 8 * MB);
    bf16* vb  = (bf16*)(ws + 16 * MB);
    bf16* wqb = (bf16*)(ws + 24 * MB);
    bf16* wkb = (bf16*)(ws + 26 * MB);
    bf16* wvb = (bf16*)(ws + 28 * MB);
    bf16* wob = (bf16*)(ws + 30 * MB);
    bf16* Qp  = (bf16*)(ws + 32 * MB);   // (B,H,S,HD) bf16
    bf16* Kpp = (bf16*)(ws + 40 * MB);   // (B,H,T,HD) bf16
    bf16* Vtp = (bf16*)(ws + 48 * MB);   // (B,H,HD,T) bf16
    bf16* Xb  = (bf16*)(ws + 56 * MB);   // attn out (B*S, C) bf16

    cvt8<<<dim3(2048, 7), 256, 0, stream>>>(query, key, value, Wq, Wk, Wv, Wo,
                                            qb, kb, vb, wqb, wkb, wvb, wob);
    gemm_qkv<<<dim3(32, 16, 3), 256, 0, stream>>>(qb, kb, vb, wqb, wkb, wvb,
                                                  bq, bk, bv, Qp, Kpp, Vtp);
    attn<<<dim3(512), 256, 0, stream>>>(Qp, Kpp, Vtp, mask, Xb);
    gemm_out<<<dim3(32, 16), 256, 0, stream>>>(Xb, wob, bo, mask, out);
}

// Round 5
// 218.027 us; speedup vs baseline: 1.0695x; 1.0139x over previous
//
#include <hip/hip_runtime.h>
#include <stdint.h>

// Problem dims (fixed by reference)
#define Bb  4
#define Ss  1024
#define Tt  1024
#define Cc  1024
#define Hh  16
#define HDd 64
#define Kk  1024   // inner dim for all projections (QIN=CTX=C=1024)

typedef __bf16 bf16;
typedef __bf16 bf16x8 __attribute__((ext_vector_type(8)));
typedef float  f32x4  __attribute__((ext_vector_type(4)));
typedef __attribute__((address_space(1))) uint32_t gu32;
typedef __attribute__((address_space(3))) uint32_t lu32;

// async global->LDS, 16B per lane; LDS dest = wave-uniform base + lane*16
__device__ __forceinline__ void load_lds16(const bf16* g, bf16* l) {
    __builtin_amdgcn_global_load_lds((gu32*)g, (lu32*)l, 16, 0, 0);
}

// raw barrier with LDS-only drain: does NOT force vmcnt(0), so global
// prefetch loads stay in flight across it (counted-vmcnt pipelining).
#define BARRIER_LDS() do {                                    \
    asm volatile("s_waitcnt lgkmcnt(0)" ::: "memory");        \
    __builtin_amdgcn_s_barrier();                             \
} while (0)

// full drain barrier (global staging complete)
#define BARRIER_VM() do {                                     \
    asm volatile("s_waitcnt vmcnt(0)" ::: "memory");          \
    __builtin_amdgcn_s_barrier();                             \
} while (0)

// ---------------------------------------------------------------------------
// fp32 -> bf16 convert, 8 elems/thread; 7 tensors via blockIdx.y
// ---------------------------------------------------------------------------
__global__ void cvt8(const float* __restrict__ s0, const float* __restrict__ s1,
                     const float* __restrict__ s2, const float* __restrict__ s3,
                     const float* __restrict__ s4, const float* __restrict__ s5,
                     const float* __restrict__ s6,
                     bf16* __restrict__ d0, bf16* __restrict__ d1,
                     bf16* __restrict__ d2, bf16* __restrict__ d3,
                     bf16* __restrict__ d4, bf16* __restrict__ d5,
                     bf16* __restrict__ d6)
{
    const float* s; bf16* d; int n;
    switch (blockIdx.y) {
        case 0: s = s0; d = d0; n = Bb * Ss * Kk; break;
        case 1: s = s1; d = d1; n = Bb * Ss * Kk; break;
        case 2: s = s2; d = d2; n = Bb * Ss * Kk; break;
        case 3: s = s3; d = d3; n = Cc * Kk; break;
        case 4: s = s4; d = d4; n = Cc * Kk; break;
        case 5: s = s5; d = d5; n = Cc * Kk; break;
        default: s = s6; d = d6; n = Cc * Kk; break;
    }
    const int i = (blockIdx.x * blockDim.x + threadIdx.x) * 8;
    if (i >= n) return;
    const float4 a = *(const float4*)(s + i);
    const float4 c = *(const float4*)(s + i + 4);
    bf16x8 o;
    o[0] = (bf16)a.x; o[1] = (bf16)a.y; o[2] = (bf16)a.z; o[3] = (bf16)a.w;
    o[4] = (bf16)c.x; o[5] = (bf16)c.y; o[6] = (bf16)c.z; o[7] = (bf16)c.w;
    *(bf16x8*)(d + i) = o;
}

// ---------------------------------------------------------------------------
// NT-GEMM mainloops, 128x64 C-tile, BK=64, XOR-swizzled LDS (chunk ^ row&7).
// LEDGER (do not re-try): R0 naive = 47.0us BEST for qkv; R1 128x128 tile =
// 60us (occupancy collapse); R2 48KB LDS dbuf = 53.8us (blocks/CU 6->3);
// R3/R4 reg-fragment-prefetch = 49.5-51.2us. The naive structure + 6
// blocks/CU TLP beats all manual pipelining at this tile size. qkv uses
// NAIVE; gemm_out (only 512 blocks = 2/CU, needs self-hiding) keeps PF.
//
// NOTE: natural blockIdx mapping kept deliberately — default round-robin
// (f%8 = XCD) gives each XCD a FIXED set of A-tiles (L2-resident) x all
// W-tiles (resident). A yy-grouping remap thrashed A (FETCH 37 -> 104 MB).
// ---------------------------------------------------------------------------
__device__ __forceinline__ void mainloop_128x64_nv(
    const bf16* __restrict__ Ab, const bf16* __restrict__ Wb,
    bf16* As, bf16* Bs, f32x4 acc[4][2])
{
    const int tid  = threadIdx.x;
    const int wid  = tid >> 6;
    const int lane = tid & 63;
    const int l16  = lane & 15;
    const int quad = lane >> 4;
    const int wm   = wid >> 1;
    const int wn   = wid & 1;
    const int r8   = lane >> 3;              // row within 8-row staging chunk
    const int ssw  = ((lane & 7) ^ r8) * 8;  // swizzled k-chunk (elems)

    for (int k0 = 0; k0 < Kk; k0 += 64) {
#pragma unroll
        for (int p = 0; p < 4; p++) {        // A: 128 rows
            const int rb = wid * 32 + p * 8;
            load_lds16(Ab + (size_t)(rb + r8) * Kk + k0 + ssw, As + rb * 64);
        }
#pragma unroll
        for (int p = 0; p < 2; p++) {        // B: 64 rows
            const int rb = wid * 16 + p * 8;
            load_lds16(Wb + (size_t)(rb + r8) * Kk + k0 + ssw, Bs + rb * 64);
        }
        __syncthreads();   // drains vmcnt(0) -> staging complete
#pragma unroll
        for (int kh = 0; kh < 2; kh++) {
            bf16x8 af[4], bw[2];
#pragma unroll
            for (int i = 0; i < 4; i++)
                af[i] = *(const bf16x8*)(As + (wm * 64 + i * 16 + l16) * 64 +
                                         (((kh * 4 + quad) ^ (l16 & 7)) * 8));
#pragma unroll
            for (int j = 0; j < 2; j++)
                bw[j] = *(const bf16x8*)(Bs + (wn * 32 + j * 16 + l16) * 64 +
                                         (((kh * 4 + quad) ^ (l16 & 7)) * 8));
#pragma unroll
            for (int i = 0; i < 4; i++)
#pragma unroll
                for (int j = 0; j < 2; j++)
                    acc[i][j] = __builtin_amdgcn_mfma_f32_16x16x32_bf16(af[i], bw[j], acc[i][j], 0, 0, 0);
        }
        __syncthreads();   // protect LDS before next stage
    }
}

// Reg-fragment-prefetch variant (kept for gemm_out: 2 blocks/CU regime)
__device__ __forceinline__ void mainloop_128x64_pf(
    const bf16* __restrict__ Ab, const bf16* __restrict__ Wb,
    bf16* As, bf16* Bs, f32x4 acc[4][2])
{
    const int tid  = threadIdx.x;
    const int wid  = tid >> 6;
    const int lane = tid & 63;
    const int l16  = lane & 15;
    const int quad = lane >> 4;
    const int wm   = wid >> 1;
    const int wn   = wid & 1;
    const int r8   = lane >> 3;
    const int ssw  = ((lane & 7) ^ r8) * 8;

    auto stage = [&](int k0) {
#pragma unroll
        for (int p = 0; p < 4; p++) {
            const int rb = wid * 32 + p * 8;
            load_lds16(Ab + (size_t)(rb + r8) * Kk + k0 + ssw, As + rb * 64);
        }
#pragma unroll
        for (int p = 0; p < 2; p++) {
            const int rb = wid * 16 + p * 8;
            load_lds16(Wb + (size_t)(rb + r8) * Kk + k0 + ssw, Bs + rb * 64);
        }
    };

    stage(0);
    BARRIER_VM();

    for (int k0 = 0; k0 < Kk; k0 += 64) {
        bf16x8 af[2][4], bw[2][2];
#pragma unroll
        for (int kh = 0; kh < 2; kh++) {
#pragma unroll
            for (int i = 0; i < 4; i++)
                af[kh][i] = *(const bf16x8*)(As + (wm * 64 + i * 16 + l16) * 64 +
                                             (((kh * 4 + quad) ^ (l16 & 7)) * 8));
#pragma unroll
            for (int j = 0; j < 2; j++)
                bw[kh][j] = *(const bf16x8*)(Bs + (wn * 32 + j * 16 + l16) * 64 +
                                             (((kh * 4 + quad) ^ (l16 & 7)) * 8));
        }
        BARRIER_LDS();
        if (k0 + 64 < Kk) stage(k0 + 64);
#pragma unroll
        for (int kh = 0; kh < 2; kh++)
#pragma unroll
            for (int i = 0; i < 4; i++)
#pragma unroll
                for (int j = 0; j < 2; j++)
                    acc[i][j] = __builtin_amdgcn_mfma_f32_16x16x32_bf16(af[kh][i], bw[kh][j], acc[i][j], 0, 0, 0);
        BARRIER_VM();
    }
}

// ---------------------------------------------------------------------------
// QKV projections with KEY COMPACTION. z selects {Q,K,V}.
// Q -> (B,H,S,HD) as before. K/V keys t are COMPACTED per batch by the key
// mask mask[b,0,t]: kept key t goes to slot j = rank[b][t] (prefix count);
// masked keys are dropped. K -> (B,H,nk..,HD) rows [0,nk); V^T -> (B,H,HD,T)
// columns [0,nk). Vtp is pre-zeroed so padded columns read as 0 in attn.
// rank is computed per-block in the epilogue (base = block-wide sum of
// mask[b,0,0..t0) + local 128-entry scan) — no extra kernel, no workspace.
// ---------------------------------------------------------------------------
__global__ __launch_bounds__(256)
void gemm_qkv(const bf16* __restrict__ Aq, const bf16* __restrict__ Ak, const bf16* __restrict__ Av,
              const bf16* __restrict__ Wq, const bf16* __restrict__ Wk, const bf16* __restrict__ Wv,
              const float* __restrict__ bq, const float* __restrict__ bk, const float* __restrict__ bv,
              const int* __restrict__ mask,
              bf16* __restrict__ Oq, bf16* __restrict__ Ok, bf16* __restrict__ Ov)
{
    __shared__ __align__(16) bf16 As[128 * 64];   // 16 KB (single buffer)
    __shared__ __align__(16) bf16 Bs[64 * 64];    // 8 KB
    __shared__ int red[256];                      // 1 KB (epilogue reduce)
    __shared__ int jj[128];                       // 0.5 KB (compacted slots)
    const int z = blockIdx.z;
    const bf16*  A    = (z == 0) ? Aq : (z == 1) ? Ak : Av;
    const bf16*  W    = (z == 0) ? Wq : (z == 1) ? Wk : Wv;
    const float* bias = (z == 0) ? bq : (z == 1) ? bk : bv;

    f32x4 acc[4][2];
    const f32x4 z4 = {0.f, 0.f, 0.f, 0.f};
#pragma unroll
    for (int i = 0; i < 4; i++)
#pragma unroll
        for (int j = 0; j < 2; j++) acc[i][j] = z4;

    mainloop_128x64_nv(A + (size_t)blockIdx.x * 128 * Kk,
                       W + (size_t)blockIdx.y * 64 * Kk, As, Bs, acc);

    const int tid = threadIdx.x;
    const int wid = tid >> 6, lane = tid & 63;
    const int l16 = lane & 15, quad = lane >> 4;
    const int wm = wid >> 1, wn = wid & 1;
    const int row0 = blockIdx.x * 128 + wm * 64;
    const int col0 = blockIdx.y * 64 + wn * 32;
    const int bb = (blockIdx.x * 128) >> 10;      // single batch per block
    const int t0 = (blockIdx.x * 128) & 1023;

    if (z != 0) {
        // rank scan for this block's 128 key rows
        const int* mrow = mask + (size_t)bb * Ss * Tt;   // mask[bb,0,t]
        int psum = 0;
        for (int t = tid; t < t0; t += 256) psum += (mrow[t] != 0);
        red[tid] = psum;
        __syncthreads();
        for (int off = 128; off > 0; off >>= 1) {
            if (tid < off) red[tid] += red[tid + off];
            __syncthreads();
        }
        const int base = red[0];
        if (tid < 128) jj[tid] = (mrow[t0 + tid] != 0);
        __syncthreads();
        if (tid == 0) {
            int a = base;
            for (int i = 0; i < 128; i++) { const int v = jj[i]; jj[i] = v ? a : -1; a += v; }
        }
        __syncthreads();
    }

#pragma unroll
    for (int j = 0; j < 2; j++) {
        const int col = col0 + j * 16 + l16;     // c = h*64 + d
        const float bj = bias[col];
        const int h = col >> 6, d = col & 63;
#pragma unroll
        for (int i = 0; i < 4; i++) {
#pragma unroll
            for (int r = 0; r < 4; r++) {
                const int local = wm * 64 + i * 16 + quad * 4 + r;   // row in block
                const int row = blockIdx.x * 128 + local;            // = bb*1024 + t
                const bf16 val = (bf16)(acc[i][j][r] + bj);
                if (z == 0) {
                    const int s = row & 1023;
                    Oq[((size_t)(bb * Hh + h) * Ss + s) * HDd + d] = val;
                } else {
                    const int jc = jj[local];
                    if (jc >= 0) {
                        if (z == 2) Ov[((size_t)((bb * Hh + h) * HDd + d)) * Tt + jc] = val;  // V^T col
                        else        Ok[((size_t)(bb * Hh + h) * Tt + jc) * HDd + d] = val;    // K row
                    }
                }
            }
        }
    }
}

// Output projection: 128x64 tile, grid (32, 16) = 512 blocks (2/CU -> PF).
// fp32 out, + bias, * rowmask (mask[b,s,0])
__global__ __launch_bounds__(256)
void gemm_out(const bf16* __restrict__ A, const bf16* __restrict__ W,
              const float* __restrict__ bias, const int* __restrict__ mask,
              float* __restrict__ out)
{
    __shared__ __align__(16) bf16 As[128 * 64];   // 16 KB
    __shared__ __align__(16) bf16 Bs[64 * 64];    // 8 KB
    f32x4 acc[4][2];
    const f32x4 z4 = {0.f, 0.f, 0.f, 0.f};
#pragma unroll
    for (int i = 0; i < 4; i++)
#pragma unroll
        for (int j = 0; j < 2; j++) acc[i][j] = z4;

    mainloop_128x64_pf(A + (size_t)blockIdx.x * 128 * Kk,
                       W + (size_t)blockIdx.y * 64 * Kk, As, Bs, acc);

    const int tid = threadIdx.x;
    const int wid = tid >> 6, lane = tid & 63;
    const int l16 = lane & 15, quad = lane >> 4;
    const int wm = wid >> 1, wn = wid & 1;
    const int row0 = blockIdx.x * 128 + wm * 64;
    const int col0 = blockIdx.y * 64 + wn * 32;
#pragma unroll
    for (int j = 0; j < 2; j++) {
        const int col = col0 + j * 16 + l16;
        const float bj = bias[col];
#pragma unroll
        for (int i = 0; i < 4; i++) {
#pragma unroll
            for (int r = 0; r < 4; r++) {
                const int row = row0 + i * 16 + quad * 4 + r;
                const float mval = (mask[(size_t)row * Tt] != 0) ? 1.f : 0.f;
                out[(size_t)row * Cc + col] = (acc[i][j][r] + bj) * mval;
            }
        }
    }
}

// ---------------------------------------------------------------------------
// Flash attention v2, QBLK=128, over COMPACTED keys.
// nk[b] (count of unmasked keys) is recomputed per block from the mask (one
// 4-load/thread reduce, ~1us). Loop runs ceil(nk/128) double-tiles (~4-5 vs
// 8): ~45% less staging+MFMA+exp work. Validity = slot < nk (no mask loads
// in the hot loop). Tail-tile garbage: K-garbage scores are select-discarded
// BEFORE exp (NaN-safe); V^T padded columns are pre-zeroed so P(=0)*V(=0)=0.
// XCD swizzle (KEEP): all 8 q-blocks of one (b,h) on one XCD.
// T14 async staging (KEEP): raw s_barrier + lgkmcnt only.
// ---------------------------------------------------------------------------
__global__ __launch_bounds__(256, 2)
void attn(const bf16* __restrict__ Q, const bf16* __restrict__ Kp, const bf16* __restrict__ Vt,
          const int* __restrict__ mask, bf16* __restrict__ X)
{
    __shared__ __align__(16) bf16 Ks[64 * 64];    // [t_local][d]  (swizzled)
    __shared__ __align__(16) bf16 Vs[64 * 64];    // [d][t_local]  (swizzled)
    __shared__ __align__(16) bf16 Ps[4][32 * 72]; // per-wave P, row stride 72
    __shared__ int red[256];
    const int g   = blockIdx.x;                   // [0,512)
    const int xcd = g & 7, idx = g >> 3;          // idx in [0,64)
    const int bh  = xcd * 8 + (idx >> 3);         // [0,64): 8 bh per XCD
    const int qblk = idx & 7;                     // q-block [0,8), 128 rows
    const int b = bh >> 4, h = bh & 15;
    const int tid = threadIdx.x, wid = tid >> 6, lane = tid & 63;
    const int l16 = lane & 15, quad = lane >> 4;
    const bf16* Qbh = Q  + (size_t)bh * Ss * HDd;
    const bf16* Kbh = Kp + (size_t)bh * Tt * HDd;
    const bf16* Vbh = Vt + (size_t)bh * HDd * Tt;
    const int*  mb  = mask + (size_t)b * Ss * Tt;  // mb[t] = mask[b,0,t]
    const int q0 = qblk * 128 + wid * 32;          // 32 rows per wave
    bf16* Psw = &Ps[wid][0];

    // nk[b]: count of unmasked keys (block-wide reduce)
    int ps = 0;
    for (int t = tid; t < Tt; t += 256) ps += (mb[t] != 0);
    red[tid] = ps;
    __syncthreads();
    for (int off = 128; off > 0; off >>= 1) {
        if (tid < off) red[tid] += red[tid + off];
        __syncthreads();
    }
    const int nkb = red[0];
    const int lim = ((nkb + 127) >> 7) << 7;       // loop bound, mult of 128

    // Q fragments (A-layout): 2 groups of 16 rows, k halves [0,32) and [32,64)
    bf16x8 qf[2][2];
#pragma unroll
    for (int u = 0; u < 2; u++) {
        qf[u][0] = *(const bf16x8*)(Qbh + (size_t)(q0 + u * 16 + l16) * HDd + quad * 8);
        qf[u][1] = *(const bf16x8*)(Qbh + (size_t)(q0 + u * 16 + l16) * HDd + 32 + quad * 8);
    }

    float ls[2][4];
    f32x4 o[2][4];
    const f32x4 z4 = {0.f, 0.f, 0.f, 0.f};
#pragma unroll
    for (int u = 0; u < 2; u++)
#pragma unroll
        for (int r = 0; r < 4; r++) ls[u][r] = 0.f;
#pragma unroll
    for (int u = 0; u < 2; u++)
#pragma unroll
        for (int dblk = 0; dblk < 4; dblk++) o[u][dblk] = z4;

    // staging lane decomposition: 8 lanes per 64-elem (128B) row
    const int srow = lane >> 3;          // 0..7: row within an 8-row chunk
    const int schk = lane & 7;           // 0..7: 16B chunk within the row
    const int sswz = (schk ^ srow) * 8;  // swizzled source element offset
    const int c80 = wid * 2, c81 = wid * 2 + 1;   // this wave's 8-row chunks

    // per-thread global bases (tile offset added per tile) and LDS dests
    const bf16* kg0 = Kbh + (size_t)(c80 * 8 + srow) * HDd + sswz;
    const bf16* kg1 = Kbh + (size_t)(c81 * 8 + srow) * HDd + sswz;
    const bf16* vg0 = Vbh + (size_t)(c80 * 8 + srow) * Tt + sswz;
    const bf16* vg1 = Vbh + (size_t)(c81 * 8 + srow) * Tt + sswz;
    bf16* kd0 = Ks + c80 * 512 + lane * 8;
    bf16* kd1 = Ks + c81 * 512 + lane * 8;
    bf16* vd0 = Vs + c80 * 512 + lane * 8;
    bf16* vd1 = Vs + c81 * 512 + lane * 8;

    bf16x8 ka0, ka1, va0, va1;              // reg buffer A
    bf16x8 kb0, kb1, vb0, vb1;              // reg buffer B

#define LOADA(KT) do { const int _kt = (KT);                          \
    ka0 = *(const bf16x8*)(kg0 + (size_t)_kt * HDd);                  \
    ka1 = *(const bf16x8*)(kg1 + (size_t)_kt * HDd);                  \
    va0 = *(const bf16x8*)(vg0 + _kt);                                \
    va1 = *(const bf16x8*)(vg1 + _kt); } while (0)
#define LOADB(KT) do { const int _kt = (KT);                          \
    kb0 = *(const bf16x8*)(kg0 + (size_t)_kt * HDd);                  \
    kb1 = *(const bf16x8*)(kg1 + (size_t)_kt * HDd);                  \
    vb0 = *(const bf16x8*)(vg0 + _kt);                                \
    vb1 = *(const bf16x8*)(vg1 + _kt); } while (0)
#define STOREA() do {                                                 \
    *(bf16x8*)kd0 = ka0; *(bf16x8*)kd1 = ka1;                         \
    *(bf16x8*)vd0 = va0; *(bf16x8*)vd1 = va1; } while (0)
#define STOREB() do {                                                 \
    *(bf16x8*)kd0 = kb0; *(bf16x8*)kd1 = kb1;                         \
    *(bf16x8*)vd0 = vb0; *(bf16x8*)vd1 = vb1; } while (0)

    auto compute = [&](int base) {
        // QK^T: 4 n-blocks of 16 keys x 2 q-groups, K-frags shared across u
        f32x4 sc[2][4];
#pragma unroll
        for (int u = 0; u < 2; u++)
#pragma unroll
            for (int nb = 0; nb < 4; nb++) sc[u][nb] = z4;
#pragma unroll
        for (int nb = 0; nb < 4; nb++) {
            const bf16* krow = Ks + (nb * 16 + l16) * 64;
            const bf16x8 kf0 = *(const bf16x8*)(krow + ((quad       ^ (l16 & 7)) * 8));
            const bf16x8 kf1 = *(const bf16x8*)(krow + (((4 + quad) ^ (l16 & 7)) * 8));
#pragma unroll
            for (int u = 0; u < 2; u++) {
                sc[u][nb] = __builtin_amdgcn_mfma_f32_16x16x32_bf16(qf[u][0], kf0, sc[u][nb], 0, 0, 0);
                sc[u][nb] = __builtin_amdgcn_mfma_f32_16x16x32_bf16(qf[u][1], kf1, sc[u][nb], 0, 0, 0);
            }
        }

        // softmax numerator + P store; validity = compacted slot < nk.
        // Select BEFORE exp output is used: invalid slots yield exactly 0
        // (NaN/garbage scores in the tail tile are discarded by the select).
#pragma unroll
        for (int nb = 0; nb < 4; nb++) {
            const bool vv = (base + nb * 16 + l16) < nkb;
#pragma unroll
            for (int u = 0; u < 2; u++) {
#pragma unroll
                for (int r = 0; r < 4; r++) {
                    const float p = vv ? __expf(sc[u][nb][r] * 0.125f) : 0.f;
                    ls[u][r] += p;
                    Psw[(u * 16 + quad * 4 + r) * 72 + nb * 16 + l16] = (bf16)p;
                }
            }
        }

        // O += P @ V : A = P (rows q), B = V^T (rows d), V-frags shared across u
#pragma unroll
        for (int kh = 0; kh < 2; kh++) {
            const bf16x8 pf0 = *(const bf16x8*)(Psw + (l16) * 72 + kh * 32 + quad * 8);
            const bf16x8 pf1 = *(const bf16x8*)(Psw + (16 + l16) * 72 + kh * 32 + quad * 8);
#pragma unroll
            for (int dblk = 0; dblk < 4; dblk++) {
                const bf16x8 vf = *(const bf16x8*)(Vs + (dblk * 16 + l16) * 64 +
                                                   (((kh * 4 + quad) ^ (l16 & 7)) * 8));
                o[0][dblk] = __builtin_amdgcn_mfma_f32_16x16x32_bf16(pf0, vf, o[0][dblk], 0, 0, 0);
                o[1][dblk] = __builtin_amdgcn_mfma_f32_16x16x32_bf16(pf1, vf, o[1][dblk], 0, 0, 0);
            }
        }
    };

    // prologue: tile 0 into reg buffer A
    LOADA(0);

    for (int kt = 0; kt < lim; kt += 128) {
        // ---- tile kt (regs A) ----
        BARRIER_LDS();                 // all waves done reading prev tile's LDS
        LOADB(kt + 64);                // kt+64 <= lim-64 <= 960: in-bounds
        STOREA();                      // compiler waits vmcnt(N) for A regs only
        BARRIER_LDS();                 // ds_writes visible to all waves
        compute(kt);

        // ---- tile kt+64 (regs B) ----
        BARRIER_LDS();
        LOADA((kt + 128 < lim) ? (kt + 128) : (lim - 64));  // last one redundant
        STOREB();
        BARRIER_LDS();
        compute(kt + 64);
    }
#undef LOADA
#undef LOADB
#undef STOREA
#undef STOREB

    // row sums: reduce ls across the 16 l16 lanes
#pragma unroll
    for (int off = 1; off <= 8; off <<= 1)
#pragma unroll
        for (int u = 0; u < 2; u++)
#pragma unroll
            for (int r = 0; r < 4; r++)
                ls[u][r] += __shfl_xor(ls[u][r], off, 64);
    float inv[2][4];
#pragma unroll
    for (int u = 0; u < 2; u++)
#pragma unroll
        for (int r = 0; r < 4; r++) inv[u][r] = 1.f / ls[u][r];

#pragma unroll
    for (int u = 0; u < 2; u++) {
#pragma unroll
        for (int dblk = 0; dblk < 4; dblk++) {
#pragma unroll
            for (int r = 0; r < 4; r++) {
                const int srow_q = q0 + u * 16 + quad * 4 + r;
                const int d = dblk * 16 + l16;
                X[(size_t)(b * Ss + srow_q) * Cc + h * HDd + d] = (bf16)(o[u][dblk][r] * inv[u][r]);
            }
        }
    }
}

// ---------------------------------------------------------------------------
extern "C" void kernel_launch(void* const* d_in, const int* in_sizes, int n_in,
                              void* d_out, int out_size, void* d_ws, size_t ws_size,
                              hipStream_t stream)
{
    const float* query = (const float*)d_in[0];
    const float* key   = (const float*)d_in[1];
    const float* value = (const float*)d_in[2];
    const int*   mask  = (const int*)d_in[3];
    const float* Wq = (const float*)d_in[4];
    const float* bq = (const float*)d_in[5];
    const float* Wk = (const float*)d_in[6];
    const float* bk = (const float*)d_in[7];
    const float* Wv = (const float*)d_in[8];
    const float* bv = (const float*)d_in[9];
    const float* Wo = (const float*)d_in[10];
    const float* bo = (const float*)d_in[11];
    float* out = (float*)d_out;

    char* ws = (char*)d_ws;
    const size_t MB = 1024 * 1024;
    bf16* qb  = (bf16*)(ws + 0 * MB);
    bf16* kb  = (bf16*)(ws + 8 * MB);
    bf16* vb  = (bf16*)(ws + 16 * MB);
    bf16* wqb = (bf16*)(ws + 24 * MB);
    bf16* wkb = (bf16*)(ws + 26 * MB);
    bf16* wvb = (bf16*)(ws + 28 * MB);
    bf16* wob = (bf16*)(ws + 30 * MB);
    bf16* Qp  = (bf16*)(ws + 32 * MB);   // (B,H,S,HD) bf16
    bf16* Kpp = (bf16*)(ws + 40 * MB);   // (B,H,T,HD) bf16, keys compacted
    bf16* Vtp = (bf16*)(ws + 48 * MB);   // (B,H,HD,T) bf16, cols compacted
    bf16* Xb  = (bf16*)(ws + 56 * MB);   // attn out (B*S, C) bf16

    // zero V^T so padded (masked-off) columns read as exact 0 in attn's tail
    hipMemsetAsync(Vtp, 0, 8 * MB, stream);

    cvt8<<<dim3(2048, 7), 256, 0, stream>>>(query, key, value, Wq, Wk, Wv, Wo,
                                            qb, kb, vb, wqb, wkb, wvb, wob);
    gemm_qkv<<<dim3(32, 16, 3), 256, 0, stream>>>(qb, kb, vb, wqb, wkb, wvb,
                                                  bq, bk, bv, mask, Qp, Kpp, Vtp);
    attn<<<dim3(512), 256, 0, stream>>>(Qp, Kpp, Vtp, mask, Xb);
    gemm_out<<<dim3(32, 16), 256, 0, stream>>>(Xb, wob, bo, mask, out);
}